// Round 8
// baseline (1123.384 us; speedup 1.0000x reference)
//
#include <hip/hip_runtime.h>
#include <hip/hip_bf16.h>
#include <hip/hip_fp16.h>
#include <math.h>

#define NN 8192
#define HIDD 768
#define NCLS 18
#define OD 512          // HEADS*GD = 2*256
#define ETOT 342        // 324 class edges + 18 self loops
#define NGRP 16         // column groups for dist kernel
#define NEG 0.2f
#define LN_EPS 1e-5f

typedef __attribute__((ext_vector_type(8))) short bf16x8;
typedef __attribute__((ext_vector_type(4))) float f32x4;

// ---------- sorted top-5 insert (static indices, stays in registers) --------
__device__ __forceinline__ void top5_insert(float s, int idx,
    float& d0, float& d1, float& d2, float& d3, float& d4,
    int& i0, int& i1, int& i2, int& i3, int& i4) {
  if (s >= d4) return;
  if (s < d3) {
    d4 = d3; i4 = i3;
    if (s < d2) {
      d3 = d2; i3 = i2;
      if (s < d1) {
        d2 = d1; i2 = i1;
        if (s < d0) { d1 = d0; i1 = i0; d0 = s; i0 = idx; }
        else        { d1 = s;  i1 = idx; }
      } else { d2 = s; i2 = idx; }
    } else { d3 = s; i3 = idx; }
  } else { d4 = s; i4 = idx; }
}

// ---------- top-8 insert on packed u32 keys (rank-based, static indices) ----
__device__ __forceinline__ void top8k_insert(unsigned key, unsigned (&kk)[8]) {
  if (key >= kk[7]) return;
  int rank = 0;
  #pragma unroll
  for (int k = 0; k < 7; ++k) rank += (key >= kk[k]) ? 1 : 0;
  #pragma unroll
  for (int k = 7; k >= 1; --k) if (k > rank) kk[k] = kk[k-1];
  #pragma unroll
  for (int k = 0; k < 8; ++k) if (k == rank) kk[k] = key;
}

// ---------- async global->LDS 16B (DMA dest never unioned, never ds_write) --
__device__ __forceinline__ void stage16(const void* g, void* l) {
  __builtin_amdgcn_global_load_lds(
      (const __attribute__((address_space(1))) unsigned int*)g,
      (__attribute__((address_space(3))) unsigned int*)l, 16, 0, 0);
}

__device__ __forceinline__ ushort f2b(float v) {
  __hip_bfloat16 b = __float2bfloat16(v);
  return *(ushort*)&b;
}

// ============ prep1 mega-kernel: all independent preamble tasks ==============
__global__ __launch_bounds__(256) void prep1_kernel(
    const float* __restrict__ X, ushort* __restrict__ Xh, float* __restrict__ x2,
    const float* __restrict__ gi_wl, const float* __restrict__ gi_wr,
    ushort* __restrict__ wlrh,
    const float* __restrict__ cemb, const float* __restrict__ gc_wl,
    const float* __restrict__ gc_bl, const float* __restrict__ gc_wr,
    const float* __restrict__ gc_br, float* __restrict__ xlc, float* __restrict__ xrc,
    const float* __restrict__ wv, const float* __restrict__ ctx_w, float* __restrict__ T1,
    const float* __restrict__ ctx_b, const float* __restrict__ bv, float* __restrict__ t1b,
    const float* __restrict__ gi_bl, const float* __restrict__ gi_br,
    float* __restrict__ bb) {
  const int bx = blockIdx.x, tid = threadIdx.x;
  if (bx < 2048) {                       // ---- rowcast + rownorm ----
    const int row = bx * 4 + (tid >> 6);
    const int lane = tid & 63;
    const float4* src = (const float4*)(X + (size_t)row * HIDD);
    ushort4* dst = (ushort4*)(Xh + (size_t)row * HIDD);
    float s = 0.f;
    #pragma unroll
    for (int q = 0; q < 3; ++q) {
      float4 v = src[lane + q * 64];
      s += v.x * v.x + v.y * v.y + v.z * v.z + v.w * v.w;
      dst[lane + q * 64] = make_ushort4(f2b(v.x), f2b(v.y), f2b(v.z), f2b(v.w));
    }
    #pragma unroll
    for (int off = 32; off; off >>= 1) s += __shfl_down(s, off);
    if (lane == 0) x2[row] = s;
  } else if (bx < 2816) {                // ---- weight casts ----
    int rel = bx - 2048;
    const float* src = gi_wl; ushort* dst = wlrh;
    if (rel >= 384) { rel -= 384; src = gi_wr; dst = wlrh + (size_t)OD * HIDD; }
    const int i = rel * 256 + tid;       // < 98304 = OD*HIDD/4
    float4 v = ((const float4*)src)[i];
    ((ushort4*)dst)[i] = make_ushort4(f2b(v.x), f2b(v.y), f2b(v.z), f2b(v.w));
  } else if (bx < 2888) {                // ---- class xlc/xrc ----
    int t = (bx - 2816) * 256 + tid;
    const float* W; const float* b; float* Y;
    if (t < NCLS * OD) { W = gc_wl; b = gc_bl; Y = xlc; }
    else { t -= NCLS * OD; W = gc_wr; b = gc_br; Y = xrc; }
    const int row = t / OD, o = t - row * OD;
    const float* xr = cemb + (size_t)row * HIDD;
    const float* wr = W + (size_t)o * HIDD;
    float acc = 0.f;
    for (int k = 0; k < HIDD; ++k) acc += xr[k] * wr[k];
    Y[t] = acc + b[o];
  } else if (bx < 4424) {                // ---- T1 = wv @ ctx_w ----
    const int idx = (bx - 2888) * 256 + tid;
    const int i = idx >> 9, j = idx & 511;
    float acc = 0.f;
    for (int k = 0; k < HIDD; ++k) acc += wv[(size_t)i * HIDD + k] * ctx_w[(size_t)k * OD + j];
    T1[idx] = acc;
  } else if (bx < 4427) {                // ---- t1b ----
    const int t = (bx - 4424) * 256 + tid;
    if (t < HIDD) {
      float acc = 0.f;
      for (int k = 0; k < HIDD; ++k) acc += ctx_b[k] * wv[(size_t)t * HIDD + k];
      t1b[t] = acc + bv[t];
    }
  } else {                               // ---- bias stack ----
    const int t = (bx - 4427) * 256 + tid;
    if (t < OD) bb[t] = gi_bl[t];
    else if (t < 2 * OD) bb[t] = gi_br[t - OD];
  }
}

// ============ prep2: W3 fold (bf16 out) + bp + class-graph GAT ===============
__global__ __launch_bounds__(256) void prep2_kernel(
    const float* __restrict__ wo, const float* __restrict__ T1,
    ushort* __restrict__ w3h, const float* __restrict__ t1b,
    const float* __restrict__ bo, float* __restrict__ bp,
    const int* __restrict__ cei, const float* __restrict__ xlc,
    const float* __restrict__ xrc, const float* __restrict__ gc_att,
    const float* __restrict__ gc_bias, float* __restrict__ cmean) {
  __shared__ float sc[ETOT * 2];
  __shared__ int es[ETOT], ed[ETOT];
  __shared__ float mx[NCLS][2], sm[NCLS][2];
  const int bx = blockIdx.x, tid = threadIdx.x;
  if (bx < 1536) {                       // ---- w3h ----
    const int idx = bx * 256 + tid;
    const int i = idx >> 9, j = idx & 511;
    float acc = 0.f;
    for (int k = 0; k < HIDD; ++k) acc += wo[(size_t)i * HIDD + k] * T1[(size_t)k * OD + j];
    w3h[idx] = f2b(acc);
  } else if (bx < 1539) {                // ---- bp ----
    const int t = (bx - 1536) * 256 + tid;
    if (t < HIDD) {
      float acc = 0.f;
      for (int k = 0; k < HIDD; ++k) acc += t1b[k] * wo[(size_t)t * HIDD + k];
      bp[t] = acc + bo[t];
    }
  } else {                               // ---- class GAT (1 block) ----
    for (int e = tid; e < ETOT; e += 256) {
      if (e < 324) { es[e] = cei[e]; ed[e] = cei[324 + e]; }
      else         { es[e] = e - 324; ed[e] = e - 324; }
    }
    __syncthreads();
    const int lane = tid & 63, w = tid >> 6;
    for (int t = w; t < ETOT * 2; t += 4) {
      const int e = t >> 1, h = t & 1;
      const float* xlr = xlc + (size_t)es[e] * OD + h * 256;
      const float* xrr = xrc + (size_t)ed[e] * OD + h * 256;
      const float* ar  = gc_att + h * 256;
      float s = 0.f;
      for (int d = lane; d < 256; d += 64) {
        float v = xlr[d] + xrr[d];
        v = v > 0.f ? v : NEG * v;
        s += v * ar[d];
      }
      #pragma unroll
      for (int off = 32; off; off >>= 1) s += __shfl_down(s, off);
      if (lane == 0) sc[t] = s;
    }
    __syncthreads();
    if (tid < NCLS * 2) {
      const int d = tid >> 1, h = tid & 1;
      float m = -3e38f;
      for (int e = 0; e < ETOT; ++e) if (ed[e] == d) m = fmaxf(m, sc[e * 2 + h]);
      float ssum = 0.f;
      for (int e = 0; e < ETOT; ++e) if (ed[e] == d) ssum += expf(sc[e * 2 + h] - m);
      mx[d][h] = m; sm[d][h] = 1.f / ssum;
    }
    __syncthreads();
    for (int t = tid; t < ETOT * 2; t += 256) {
      const int e = t >> 1, h = t & 1;
      sc[t] = expf(sc[t] - mx[ed[e]][h]) * sm[ed[e]][h];
    }
    __syncthreads();
    for (int c = tid; c < OD; c += 256) {
      const int h = c >> 8;
      float acc = 0.f;
      for (int e = 0; e < ETOT; ++e) acc += sc[e * 2 + h] * xlc[(size_t)es[e] * OD + c];
      cmean[c] = acc * (1.f / 18.f) + gc_bias[c];
    }
  }
}

// ---------- stage 1: bf16 MFMA distances + per-row approx top-8 (packed keys)
// m97-structure: global_load_lds DMA staging (sA/sB dedicated, never unioned,
// never ds_written). Dk score tile is a SEPARATE 16 KB buffer, written/scanned
// in two 64-col phases; it unions only the plain-ds merge scratch (proven).
// LDS 48.5 KB -> 3 blocks/CU (m97's occupancy). 2 barriers per K-step.
__global__ __launch_bounds__(256) void dist_topk_mfma(
    const ushort* __restrict__ Xh, const float* __restrict__ x2,
    unsigned* __restrict__ pck) {
  __shared__ char sA[16384];                  // DMA-only
  __shared__ char sB[16384];                  // DMA-only
  __shared__ __align__(16) char scr[16384];   // Dk [128][64] u16 ∪ ck [256][8] u32
  __shared__ float c2s[128];
  ushort* const Dk = (ushort*)scr;
  unsigned* const ck = (unsigned*)scr;

  const int tid = threadIdx.x;
  const int lane = tid & 63, wid = tid >> 6;
  const int fr = lane & 15, fq = lane >> 4;
  const int r0 = blockIdx.x * 128;
  const int grp = blockIdx.y;
  const int wr = (wid >> 1) * 64, wc = (wid & 1) * 64;

  unsigned keys[8];
  #pragma unroll
  for (int k = 0; k < 8; ++k) keys[k] = 0xFFFFFFFFu;

  for (int jt = 0; jt < (NN / NGRP) / 128; ++jt) {
    const int c0 = grp * (NN / NGRP) + jt * 128;
    __syncthreads();                         // prev jt scan done (Dk/c2s free)
    if (tid < 128) c2s[tid] = x2[c0 + tid];
    f32x4 acc[4][4] = {};
    for (int kt = 0; kt < HIDD; kt += 64) {
      __syncthreads();                       // frag reads of prev kt done
      #pragma unroll
      for (int q = 0; q < 4; ++q) {
        const int chunk = wid * 256 + q * 64 + lane;
        const int row = chunk >> 3;
        const int lc = (chunk & 7) ^ (row & 7);   // pre-swizzled source
        const int ld = wid * 4096 + q * 1024;
        stage16((const char*)Xh + ((size_t)(r0 + row) * HIDD + kt) * 2 + (size_t)lc * 16, sA + ld);
        stage16((const char*)Xh + ((size_t)(c0 + row) * HIDD + kt) * 2 + (size_t)lc * 16, sB + ld);
      }
      __syncthreads();                       // vmcnt drained -> staged visible
      #pragma unroll
      for (int kk = 0; kk < 2; ++kk) {
        bf16x8 bh[4];
        #pragma unroll
        for (int n = 0; n < 4; ++n) {
          const int br = wc + n * 16 + fr;
          bh[n] = *(const bf16x8*)(sB + br * 128 + (((kk * 4 + fq) ^ (br & 7)) << 4));
        }
        #pragma unroll
        for (int m = 0; m < 4; ++m) {
          const int ar = wr + m * 16 + fr;
          const bf16x8 a = *(const bf16x8*)(sA + ar * 128 + (((kk * 4 + fq) ^ (ar & 7)) << 4));
          #pragma unroll
          for (int n = 0; n < 4; ++n)
            acc[m][n] = __builtin_amdgcn_mfma_f32_16x16x32_bf16(a, bh[n], acc[m][n], 0, 0, 0);
        }
      }
    }
    // ---- two half-tile key phases: cols [0,64) then [64,128) ----
    #pragma unroll
    for (int ph = 0; ph < 2; ++ph) {
      if ((wid & 1) == ph) {                 // this wave's wc matches the phase
        #pragma unroll
        for (int n = 0; n < 4; ++n) {
          const int cl = n * 16 + fr;        // local col within the half
          const float c2 = c2s[wc + cl] - 768.0f;
          #pragma unroll
          for (int m = 0; m < 4; ++m) {
            #pragma unroll
            for (int j = 0; j < 4; ++j) {
              const int row = wr + m * 16 + fq * 4 + j;
              const float s = c2 - 2.0f * acc[m][n][j];
              const ushort u = __half_as_ushort(__float2half(s));
              const ushort k16 = (u & 0x8000) ? (ushort)(~u) : (ushort)(u | 0x8000);
              Dk[row * 64 + ((cl + row) & 63)] = k16;
            }
          }
        }
      }
      __syncthreads();                       // keys visible
      {                                      // scan: 2 threads/row, 32 cols each
        const int r = tid >> 1, h = tid & 1;
        const int gbase = c0 + ph * 64;
        #pragma unroll 4
        for (int c = 0; c < 32; ++c) {
          const int lc = h * 32 + c;
          const unsigned key =
              ((unsigned)Dk[r * 64 + ((lc + r) & 63)] << 16) | (unsigned)(gbase + lc);
          top8k_insert(key, keys);
        }
      }
      __syncthreads();                       // scan done before next write/jt
    }
  }
  // ---- merge the two per-row scan threads (ck unions Dk; barrier-guarded) ----
  #pragma unroll
  for (int k = 0; k < 8; ++k) ck[tid * 8 + k] = keys[k];
  __syncthreads();
  if (tid < 128) {
    unsigned mk[8];
    #pragma unroll
    for (int k = 0; k < 8; ++k) mk[k] = ck[(2 * tid) * 8 + k];
    #pragma unroll
    for (int k = 0; k < 8; ++k) top8k_insert(ck[(2 * tid + 1) * 8 + k], mk);
    const size_t base = ((size_t)grp * NN + (r0 + tid)) * 8;   // [g][row][8]
    #pragma unroll
    for (int k = 0; k < 8; ++k) pck[base + k] = mk[k];
  }
}

// ---------- merge NGRP key lists -> per-row top-8 candidate indices ----------
__global__ __launch_bounds__(256) void cand_merge_kernel(const unsigned* __restrict__ pck,
    int* __restrict__ cand) {
  const int row = blockIdx.x * 256 + threadIdx.x;
  if (row >= NN) return;
  unsigned best[8];
  #pragma unroll
  for (int k = 0; k < 8; ++k) best[k] = 0xFFFFFFFFu;
  for (int g = 0; g < NGRP; ++g) {
    const size_t base = ((size_t)g * NN + row) * 8;
    #pragma unroll
    for (int k = 0; k < 8; ++k) top8k_insert(pck[base + k], best);
  }
  #pragma unroll
  for (int k = 0; k < 8; ++k) cand[row * 8 + k] = (int)(best[k] & 0xFFFFu);
}

// ---------- stage 2: exact fp32 refine of 8 candidates -> exact top-5 --------
__global__ __launch_bounds__(256) void refine_kernel(const float* __restrict__ X,
    const float* __restrict__ x2, const int* __restrict__ cand, int* __restrict__ knn) {
  const int row = blockIdx.x * 4 + (threadIdx.x >> 6);
  const int lane = threadIdx.x & 63;
  int c[8];
  #pragma unroll
  for (int k = 0; k < 8; ++k) c[k] = cand[row * 8 + k];
  const float4* xi = (const float4*)(X + (size_t)row * HIDD);
  float acc[8] = {};
  #pragma unroll
  for (int q = 0; q < 3; ++q) {
    const float4 a = xi[lane + q * 64];
    #pragma unroll
    for (int k = 0; k < 8; ++k) {
      const float4 b = ((const float4*)(X + (size_t)c[k] * HIDD))[lane + q * 64];
      acc[k] += a.x * b.x + a.y * b.y + a.z * b.z + a.w * b.w;
    }
  }
  #pragma unroll
  for (int k = 0; k < 8; ++k) {
    #pragma unroll
    for (int off = 32; off; off >>= 1) acc[k] += __shfl_down(acc[k], off);
  }
  if (lane == 0) {
    float d0 = 3e38f, d1 = 3e38f, d2 = 3e38f, d3 = 3e38f, d4 = 3e38f;
    int i0 = 0, i1 = 0, i2 = 0, i3 = 0, i4 = 0;
    #pragma unroll
    for (int k = 0; k < 8; ++k) {
      const float s = x2[c[k]] - 2.0f * acc[k];
      top5_insert(s, c[k], d0, d1, d2, d3, d4, i0, i1, i2, i3, i4);
    }
    knn[row * 5 + 0] = i0; knn[row * 5 + 1] = i1; knn[row * 5 + 2] = i2;
    knn[row * 5 + 3] = i3; knn[row * 5 + 4] = i4;
  }
}

// ---------- bf16 MFMA GEMM: C[8192,Nc] = A @ B^T + bias ----------------------
__global__ __launch_bounds__(256) void gemm_nt_mfma(const ushort* __restrict__ A,
    const ushort* __restrict__ B, const float* __restrict__ bias,
    float* __restrict__ C, int Nc, int K) {
  __shared__ char lds[32768];
  char* const pA = lds;
  char* const pB = lds + 16384;
  const int tid = threadIdx.x;
  const int lane = tid & 63, wid = tid >> 6;
  const int fr = lane & 15, fq = lane >> 4;
  const int r0 = blockIdx.x * 128;
  const int c0 = blockIdx.y * 128;
  const int wr = (wid >> 1) * 64, wc = (wid & 1) * 64;
  f32x4 acc[4][4] = {};
  for (int kt = 0; kt < K; kt += 64) {
    __syncthreads();
    #pragma unroll
    for (int q = 0; q < 4; ++q) {
      const int chunk = wid * 256 + q * 64 + lane;
      const int row = chunk >> 3;
      const int lc = (chunk & 7) ^ (row & 7);
      const int ld = wid * 4096 + q * 1024;
      stage16((const char*)A + ((size_t)(r0 + row) * K + kt) * 2 + (size_t)lc * 16, pA + ld);
      stage16((const char*)B + ((size_t)(c0 + row) * K + kt) * 2 + (size_t)lc * 16, pB + ld);
    }
    __syncthreads();
    #pragma unroll
    for (int kk = 0; kk < 2; ++kk) {
      bf16x8 ah[4], bh[4];
      #pragma unroll
      for (int m = 0; m < 4; ++m) {
        const int ar = wr + m * 16 + fr;
        ah[m] = *(const bf16x8*)(pA + ar * 128 + (((kk * 4 + fq) ^ (ar & 7)) << 4));
      }
      #pragma unroll
      for (int n = 0; n < 4; ++n) {
        const int br = wc + n * 16 + fr;
        bh[n] = *(const bf16x8*)(pB + br * 128 + (((kk * 4 + fq) ^ (br & 7)) << 4));
      }
      #pragma unroll
      for (int m = 0; m < 4; ++m)
        #pragma unroll
        for (int n = 0; n < 4; ++n)
          acc[m][n] = __builtin_amdgcn_mfma_f32_16x16x32_bf16(ah[m], bh[n], acc[m][n], 0, 0, 0);
    }
  }
  #pragma unroll
  for (int n = 0; n < 4; ++n) {
    const int cc = c0 + wc + n * 16 + fr;
    const float bs = bias[cc];
    #pragma unroll
    for (int m = 0; m < 4; ++m) {
      #pragma unroll
      for (int j = 0; j < 4; ++j) {
        const int rr = r0 + wr + m * 16 + fq * 4 + j;
        C[(size_t)rr * Nc + cc] = acc[m][n][j] + bs;
      }
    }
  }
}

// ---------- instance GATv2; xlr packed [N][1024]; ctx written bf16 -----------
__global__ __launch_bounds__(256) void inst_gat_kernel(const float* __restrict__ xlr,
    const int* __restrict__ knn, const float* __restrict__ att,
    const float* __restrict__ bias, const float* __restrict__ cmean,
    ushort* __restrict__ ctxh) {
  __shared__ float rows[7][512];   // 6 neighbor xl rows + own xr row
  __shared__ float sc[12];
  __shared__ float alpha[12];
  __shared__ int nbr[6];
  const int i = blockIdx.x;
  const int tid = threadIdx.x;
  if (tid < 5) nbr[tid] = knn[i * 5 + tid];
  else if (tid == 5) nbr[5] = i;   // explicit self loop
  __syncthreads();
  for (int t = tid; t < 7 * 128; t += 256) {
    const int rr = t >> 7, e4 = t & 127;
    const float* src = (rr < 6) ? (xlr + (size_t)nbr[rr] * 1024)
                                : (xlr + (size_t)i * 1024 + 512);
    ((float4*)rows[rr])[e4] = ((const float4*)src)[e4];
  }
  __syncthreads();
  const int lane = tid & 63, w = tid >> 6;
  for (int t = w; t < 12; t += 4) {
    const int e = t >> 1, h = t & 1;
    const float* ar = att + h * 256;
    float s = 0.f;
    #pragma unroll
    for (int q = 0; q < 4; ++q) {
      const int d = lane + q * 64;
      float v = rows[e][h * 256 + d] + rows[6][h * 256 + d];
      v = v > 0.f ? v : NEG * v;
      s += v * ar[d];
    }
    #pragma unroll
    for (int off = 32; off; off >>= 1) s += __shfl_down(s, off);
    if (lane == 0) sc[t] = s;
  }
  __syncthreads();
  if (tid < 2) {
    const int h = tid;
    float m = -3e38f;
    #pragma unroll
    for (int e = 0; e < 6; ++e) m = fmaxf(m, sc[e * 2 + h]);
    float ssum = 0.f;
    #pragma unroll
    for (int e = 0; e < 6; ++e) { float ex = expf(sc[e * 2 + h] - m); alpha[e * 2 + h] = ex; ssum += ex; }
    const float inv = 1.f / ssum;
    #pragma unroll
    for (int e = 0; e < 6; ++e) alpha[e * 2 + h] *= inv;
  }
  __syncthreads();
  for (int c = tid; c < OD; c += 256) {
    const int h = c >> 8;
    float acc = 0.f;
    #pragma unroll
    for (int e = 0; e < 6; ++e) acc += alpha[e * 2 + h] * rows[e][c];
    ctxh[(size_t)i * OD + c] = f2b(acc + bias[c] + cmean[c]);
  }
}

// ---------- fused epilogue: LN1 -> LN2 -> GELU -> 18-way classifier ----------
__global__ __launch_bounds__(256) void epilogue_kernel(const float* __restrict__ inst,
    const float* __restrict__ attn, const float* __restrict__ g1, const float* __restrict__ b1,
    const float* __restrict__ g2, const float* __restrict__ b2, const float* __restrict__ gw,
    const float* __restrict__ gb, const float* __restrict__ temp, float* __restrict__ out) {
  __shared__ float buf[HIDD];
  __shared__ float red[4];
  const int i = blockIdx.x;
  const int tid = threadIdx.x;
  const int lane = tid & 63, w = tid >> 6;
  size_t base = (size_t)i * HIDD;
  float v0 = inst[base + tid]       + attn[base + tid];
  float v1 = inst[base + tid + 256] + attn[base + tid + 256];
  float v2 = inst[base + tid + 512] + attn[base + tid + 512];

  float s = v0 + v1 + v2;
  #pragma unroll
  for (int off = 32; off; off >>= 1) s += __shfl_down(s, off);
  if (lane == 0) red[w] = s;
  __syncthreads();
  float mean = (red[0] + red[1] + red[2] + red[3]) * (1.f / HIDD);
  __syncthreads();
  float e0 = v0 - mean, e1 = v1 - mean, e2 = v2 - mean;
  s = e0 * e0 + e1 * e1 + e2 * e2;
  #pragma unroll
  for (int off = 32; off; off >>= 1) s += __shfl_down(s, off);
  if (lane == 0) red[w] = s;
  __syncthreads();
  float rstd = rsqrtf((red[0] + red[1] + red[2] + red[3]) * (1.f / HIDD) + LN_EPS);
  __syncthreads();
  float y0 = e0 * rstd * g1[tid]       + b1[tid];
  float y1 = e1 * rstd * g1[tid + 256] + b1[tid + 256];
  float y2 = e2 * rstd * g1[tid + 512] + b1[tid + 512];

  s = y0 + y1 + y2;
  #pragma unroll
  for (int off = 32; off; off >>= 1) s += __shfl_down(s, off);
  if (lane == 0) red[w] = s;
  __syncthreads();
  float mean2 = (red[0] + red[1] + red[2] + red[3]) * (1.f / HIDD);
  __syncthreads();
  float f0 = y0 - mean2, f1 = y1 - mean2, f2 = y2 - mean2;
  s = f0 * f0 + f1 * f1 + f2 * f2;
  #pragma unroll
  for (int off = 32; off; off >>= 1) s += __shfl_down(s, off);
  if (lane == 0) red[w] = s;
  __syncthreads();
  float rstd2 = rsqrtf((red[0] + red[1] + red[2] + red[3]) * (1.f / HIDD) + LN_EPS);
  float z0 = f0 * rstd2 * g2[tid]       + b2[tid];
  float z1 = f1 * rstd2 * g2[tid + 256] + b2[tid + 256];
  float z2 = f2 * rstd2 * g2[tid + 512] + b2[tid + 512];
  buf[tid]       = 0.5f * z0 * (1.f + erff(z0 * 0.70710678118654752f));
  buf[tid + 256] = 0.5f * z1 * (1.f + erff(z1 * 0.70710678118654752f));
  buf[tid + 512] = 0.5f * z2 * (1.f + erff(z2 * 0.70710678118654752f));
  __syncthreads();

  float invT = 1.f / temp[0];
  for (int c = w; c < NCLS; c += 4) {
    const float* wr = gw + (size_t)c * HIDD;
    float acc = 0.f;
    for (int d = lane; d < HIDD; d += 64) acc += buf[d] * wr[d];
    #pragma unroll
    for (int off = 32; off; off >>= 1) acc += __shfl_down(acc, off);
    if (lane == 0) out[(size_t)i * NCLS + c] = (acc + gb[c]) * invT;
  }
}

// ---------------------------------------------------------------------------
extern "C" void kernel_launch(void* const* d_in, const int* in_sizes, int n_in,
                              void* d_out, int out_size, void* d_ws, size_t ws_size,
                              hipStream_t stream) {
  (void)in_sizes; (void)n_in; (void)out_size; (void)ws_size;
  const float* X       = (const float*)d_in[0];
  const int*   cei     = (const int*)  d_in[1];
  const float* cemb    = (const float*)d_in[2];
  const float* gc_wl   = (const float*)d_in[3];
  const float* gc_bl   = (const float*)d_in[4];
  const float* gc_wr   = (const float*)d_in[5];
  const float* gc_br   = (const float*)d_in[6];
  const float* gc_att  = (const float*)d_in[7];
  const float* gc_bias = (const float*)d_in[8];
  const float* gi_wl   = (const float*)d_in[9];
  const float* gi_bl   = (const float*)d_in[10];
  const float* gi_wr   = (const float*)d_in[11];
  const float* gi_br   = (const float*)d_in[12];
  const float* gi_att  = (const float*)d_in[13];
  const float* gi_bias = (const float*)d_in[14];
  // d_in[15]=q_w, d_in[16]=q_b: cancel out of the forward value (seq_len 1)
  const float* ctx_w   = (const float*)d_in[17];
  const float* ctx_b   = (const float*)d_in[18];
  const float* wv      = (const float*)d_in[19];
  const float* bv      = (const float*)d_in[20];
  const float* wo      = (const float*)d_in[21];
  const float* bo      = (const float*)d_in[22];
  const float* ln1_g   = (const float*)d_in[23];
  const float* ln1_b   = (const float*)d_in[24];
  const float* ln2_g   = (const float*)d_in[25];
  const float* ln2_b   = (const float*)d_in[26];
  const float* gw_w    = (const float*)d_in[27];
  const float* gw_b    = (const float*)d_in[28];
  const float* temp    = (const float*)d_in[29];
  float* out = (float*)d_out;

  // ---- workspace layout (f32 units). R1,R2,R3 are 4.19M f32 each. ----
  // Order: prep1, prep2, dist, merge, refine, gemm_xlr, inst_gat, gemm_attn, epi
  // R1: pck (dist->merge) -> xlr head (gemm->inst_gat) -> attnb head
  // R2: T1 (prep1->prep2) -> xlr tail -> attnb mid
  // R3: Xh+wlrh (prep1 -> dist/gemm) -> ctxh (inst_gat->gemm_attn)
  // R4: x2, w3h, t1b, bp, bb, cand, knn, xlc, xrc, cmean (no overlays)
  float* ws  = (float*)d_ws;
  float* R1  = ws;
  float* R2  = R1 + (size_t)NN * OD;
  float* R3  = R2 + (size_t)NN * OD;
  float* R4  = R3 + (size_t)NN * OD;

  // R4 sublayout
  float* x2    = R4;                                   // 8192
  ushort* w3h  = (ushort*)(x2 + NN);                   // 768*512 bf16
  float* t1b   = (float*)(w3h + (size_t)HIDD * OD);    // 768
  float* bp    = t1b + HIDD;                           // 768
  float* bb    = bp + HIDD;                            // 1024 stacked bias
  int*   cand  = (int*)(bb + 2 * OD);                  // 8192*8
  int*   knn   = cand + NN * 8;                        // 8192*5
  float* xlc   = (float*)(knn + NN * 5);               // 18*512
  float* xrc   = xlc + NCLS * OD;                      // 18*512
  float* cmean = xrc + NCLS * OD;                      // 512

  // aliases
  unsigned* pck = (unsigned*)R1;                       // [16][8192][8] u32 = 4 MB
  float* xlr   = R1;                                   // 8192*1024 f32 (R1+R2)
  float* attnb = R1;                                   // 8192*768 f32 (R1+R2 head)
  float* T1    = R2;                                   // 768*512 f32 (dead before xlr)
  ushort* Xh   = (ushort*)R3;                          // 8192*768 bf16
  ushort* wlrh = (ushort*)(R3 + (size_t)NN * HIDD / 2);// 1024*768 bf16 stacked wl|wr
  ushort* ctxh = (ushort*)R3;                          // 8192*512 bf16 (Xh dead)

  // 1) all independent preamble tasks
  prep1_kernel<<<4431, 256, 0, stream>>>(X, Xh, x2, gi_wl, gi_wr, wlrh,
      cemb, gc_wl, gc_bl, gc_wr, gc_br, xlc, xrc,
      wv, ctx_w, T1, ctx_b, bv, t1b, gi_bl, gi_br, bb);
  // 2) W3 fold (bf16 out) + bp + class GAT
  prep2_kernel<<<1540, 256, 0, stream>>>(wo, T1, w3h, t1b, bo, bp,
      cei, xlc, xrc, gc_att, gc_bias, cmean);
  // 3) kNN approx pass (DMA-staged MFMA + packed-key top-8)
  dist_topk_mfma<<<dim3(NN / 128, NGRP), 256, 0, stream>>>(Xh, x2, pck);
  // 4) merge candidate lists (pck dead after)
  cand_merge_kernel<<<NN / 256, 256, 0, stream>>>(pck, cand);
  // 5) exact fp32 refine -> knn
  refine_kernel<<<NN / 4, 256, 0, stream>>>(X, x2, cand, knn);
  // 6) fused xl|xr projection (overwrites pck region)
  gemm_nt_mfma<<<dim3(NN / 128, (2 * OD) / 128), 256, 0, stream>>>(Xh, wlrh, bb, xlr, 2 * OD, HIDD);
  // 7) GAT aggregate -> ctxh bf16 (overwrites Xh region; Xh dead)
  inst_gat_kernel<<<NN, 256, 0, stream>>>(xlr, knn, gi_att, gi_bias, cmean, ctxh);
  // 8) attn = ctxh @ w3h^T + bp (xlr dead; attnb overlays R1+R2)
  gemm_nt_mfma<<<dim3(NN / 128, HIDD / 128), 256, 0, stream>>>(ctxh, w3h, bp, attnb, HIDD, OD);
  // 9) LN -> LN -> GELU -> classifier
  epilogue_kernel<<<NN, 256, 0, stream>>>(X, attnb, ln1_g, ln1_b, ln2_g, ln2_b, gw_w, gw_b, temp, out);
}

// Round 9
// 824.544 us; speedup vs baseline: 1.3624x; 1.3624x over previous
//
#include <hip/hip_runtime.h>
#include <hip/hip_bf16.h>
#include <hip/hip_fp16.h>
#include <math.h>

#define NN 8192
#define HIDD 768
#define NCLS 18
#define OD 512          // HEADS*GD = 2*256
#define ETOT 342        // 324 class edges + 18 self loops
#define NGRP 16         // column groups for dist kernel
#define NEG 0.2f
#define LN_EPS 1e-5f

typedef __attribute__((ext_vector_type(8))) short bf16x8;
typedef __attribute__((ext_vector_type(4))) float f32x4;

// ---------- sorted top-5 insert (static indices, stays in registers) --------
__device__ __forceinline__ void top5_insert(float s, int idx,
    float& d0, float& d1, float& d2, float& d3, float& d4,
    int& i0, int& i1, int& i2, int& i3, int& i4) {
  if (s >= d4) return;
  if (s < d3) {
    d4 = d3; i4 = i3;
    if (s < d2) {
      d3 = d2; i3 = i2;
      if (s < d1) {
        d2 = d1; i2 = i1;
        if (s < d0) { d1 = d0; i1 = i0; d0 = s; i0 = idx; }
        else        { d1 = s;  i1 = idx; }
      } else { d2 = s; i2 = idx; }
    } else { d3 = s; i3 = idx; }
  } else { d4 = s; i4 = idx; }
}

// ---------- top-8 insert on packed u32 keys (rank-based, static indices) ----
__device__ __forceinline__ void top8k_insert(unsigned key, unsigned (&kk)[8]) {
  if (key >= kk[7]) return;
  int rank = 0;
  #pragma unroll
  for (int k = 0; k < 7; ++k) rank += (key >= kk[k]) ? 1 : 0;
  #pragma unroll
  for (int k = 7; k >= 1; --k) if (k > rank) kk[k] = kk[k-1];
  #pragma unroll
  for (int k = 0; k < 8; ++k) if (k == rank) kk[k] = key;
}

// ---------- async global->LDS 16B (used only in gemm_nt_mfma) ---------------
__device__ __forceinline__ void stage16(const void* g, void* l) {
  __builtin_amdgcn_global_load_lds(
      (const __attribute__((address_space(1))) unsigned int*)g,
      (__attribute__((address_space(3))) unsigned int*)l, 16, 0, 0);
}

__device__ __forceinline__ ushort f2b(float v) {
  __hip_bfloat16 b = __float2bfloat16(v);
  return *(ushort*)&b;
}

// ============ prep1 mega-kernel: all independent preamble tasks ==============
__global__ __launch_bounds__(256) void prep1_kernel(
    const float* __restrict__ X, ushort* __restrict__ Xh, float* __restrict__ x2,
    const float* __restrict__ gi_wl, const float* __restrict__ gi_wr,
    ushort* __restrict__ wlrh,
    const float* __restrict__ cemb, const float* __restrict__ gc_wl,
    const float* __restrict__ gc_bl, const float* __restrict__ gc_wr,
    const float* __restrict__ gc_br, float* __restrict__ xlc, float* __restrict__ xrc,
    const float* __restrict__ wv, const float* __restrict__ ctx_w, float* __restrict__ T1,
    const float* __restrict__ ctx_b, const float* __restrict__ bv, float* __restrict__ t1b,
    const float* __restrict__ gi_bl, const float* __restrict__ gi_br,
    float* __restrict__ bb) {
  const int bx = blockIdx.x, tid = threadIdx.x;
  if (bx < 2048) {                       // ---- rowcast + rownorm ----
    const int row = bx * 4 + (tid >> 6);
    const int lane = tid & 63;
    const float4* src = (const float4*)(X + (size_t)row * HIDD);
    ushort4* dst = (ushort4*)(Xh + (size_t)row * HIDD);
    float s = 0.f;
    #pragma unroll
    for (int q = 0; q < 3; ++q) {
      float4 v = src[lane + q * 64];
      s += v.x * v.x + v.y * v.y + v.z * v.z + v.w * v.w;
      dst[lane + q * 64] = make_ushort4(f2b(v.x), f2b(v.y), f2b(v.z), f2b(v.w));
    }
    #pragma unroll
    for (int off = 32; off; off >>= 1) s += __shfl_down(s, off);
    if (lane == 0) x2[row] = s;
  } else if (bx < 2816) {                // ---- weight casts ----
    int rel = bx - 2048;
    const float* src = gi_wl; ushort* dst = wlrh;
    if (rel >= 384) { rel -= 384; src = gi_wr; dst = wlrh + (size_t)OD * HIDD; }
    const int i = rel * 256 + tid;       // < 98304 = OD*HIDD/4
    float4 v = ((const float4*)src)[i];
    ((ushort4*)dst)[i] = make_ushort4(f2b(v.x), f2b(v.y), f2b(v.z), f2b(v.w));
  } else if (bx < 2888) {                // ---- class xlc/xrc ----
    int t = (bx - 2816) * 256 + tid;
    const float* W; const float* b; float* Y;
    if (t < NCLS * OD) { W = gc_wl; b = gc_bl; Y = xlc; }
    else { t -= NCLS * OD; W = gc_wr; b = gc_br; Y = xrc; }
    const int row = t / OD, o = t - row * OD;
    const float* xr = cemb + (size_t)row * HIDD;
    const float* wr = W + (size_t)o * HIDD;
    float acc = 0.f;
    for (int k = 0; k < HIDD; ++k) acc += xr[k] * wr[k];
    Y[t] = acc + b[o];
  } else if (bx < 4424) {                // ---- T1 = wv @ ctx_w ----
    const int idx = (bx - 2888) * 256 + tid;
    const int i = idx >> 9, j = idx & 511;
    float acc = 0.f;
    for (int k = 0; k < HIDD; ++k) acc += wv[(size_t)i * HIDD + k] * ctx_w[(size_t)k * OD + j];
    T1[idx] = acc;
  } else if (bx < 4427) {                // ---- t1b ----
    const int t = (bx - 4424) * 256 + tid;
    if (t < HIDD) {
      float acc = 0.f;
      for (int k = 0; k < HIDD; ++k) acc += ctx_b[k] * wv[(size_t)t * HIDD + k];
      t1b[t] = acc + bv[t];
    }
  } else {                               // ---- bias stack ----
    const int t = (bx - 4427) * 256 + tid;
    if (t < OD) bb[t] = gi_bl[t];
    else if (t < 2 * OD) bb[t] = gi_br[t - OD];
  }
}

// ============ prep2: W3 fold (bf16 out) + bp + class-graph GAT ===============
__global__ __launch_bounds__(256) void prep2_kernel(
    const float* __restrict__ wo, const float* __restrict__ T1,
    ushort* __restrict__ w3h, const float* __restrict__ t1b,
    const float* __restrict__ bo, float* __restrict__ bp,
    const int* __restrict__ cei, const float* __restrict__ xlc,
    const float* __restrict__ xrc, const float* __restrict__ gc_att,
    const float* __restrict__ gc_bias, float* __restrict__ cmean) {
  __shared__ float sc[ETOT * 2];
  __shared__ int es[ETOT], ed[ETOT];
  __shared__ float mx[NCLS][2], sm[NCLS][2];
  const int bx = blockIdx.x, tid = threadIdx.x;
  if (bx < 1536) {                       // ---- w3h ----
    const int idx = bx * 256 + tid;
    const int i = idx >> 9, j = idx & 511;
    float acc = 0.f;
    for (int k = 0; k < HIDD; ++k) acc += wo[(size_t)i * HIDD + k] * T1[(size_t)k * OD + j];
    w3h[idx] = f2b(acc);
  } else if (bx < 1539) {                // ---- bp ----
    const int t = (bx - 1536) * 256 + tid;
    if (t < HIDD) {
      float acc = 0.f;
      for (int k = 0; k < HIDD; ++k) acc += t1b[k] * wo[(size_t)t * HIDD + k];
      bp[t] = acc + bo[t];
    }
  } else {                               // ---- class GAT (1 block) ----
    for (int e = tid; e < ETOT; e += 256) {
      if (e < 324) { es[e] = cei[e]; ed[e] = cei[324 + e]; }
      else         { es[e] = e - 324; ed[e] = e - 324; }
    }
    __syncthreads();
    const int lane = tid & 63, w = tid >> 6;
    for (int t = w; t < ETOT * 2; t += 4) {
      const int e = t >> 1, h = t & 1;
      const float* xlr = xlc + (size_t)es[e] * OD + h * 256;
      const float* xrr = xrc + (size_t)ed[e] * OD + h * 256;
      const float* ar  = gc_att + h * 256;
      float s = 0.f;
      for (int d = lane; d < 256; d += 64) {
        float v = xlr[d] + xrr[d];
        v = v > 0.f ? v : NEG * v;
        s += v * ar[d];
      }
      #pragma unroll
      for (int off = 32; off; off >>= 1) s += __shfl_down(s, off);
      if (lane == 0) sc[t] = s;
    }
    __syncthreads();
    if (tid < NCLS * 2) {
      const int d = tid >> 1, h = tid & 1;
      float m = -3e38f;
      for (int e = 0; e < ETOT; ++e) if (ed[e] == d) m = fmaxf(m, sc[e * 2 + h]);
      float ssum = 0.f;
      for (int e = 0; e < ETOT; ++e) if (ed[e] == d) ssum += expf(sc[e * 2 + h] - m);
      mx[d][h] = m; sm[d][h] = 1.f / ssum;
    }
    __syncthreads();
    for (int t = tid; t < ETOT * 2; t += 256) {
      const int e = t >> 1, h = t & 1;
      sc[t] = expf(sc[t] - mx[ed[e]][h]) * sm[ed[e]][h];
    }
    __syncthreads();
    for (int c = tid; c < OD; c += 256) {
      const int h = c >> 8;
      float acc = 0.f;
      for (int e = 0; e < ETOT; ++e) acc += sc[e * 2 + h] * xlc[(size_t)es[e] * OD + c];
      cmean[c] = acc * (1.f / 18.f) + gc_bias[c];
    }
  }
}

// ---------- stage 1: bf16 MFMA distances + per-row approx top-8 (packed keys)
// ROUND-6 WINNER restored verbatim: reg-staged (no DMA, no prefetch), 33 KB
// LDS (score tile unions staging via plain ds ops + barriers), forced
// <=128 VGPR -> 4 blocks/CU. Measured 295 us / occupancy 43% / VGPR 64.
__global__ __launch_bounds__(256, 4) void dist_topk_mfma(
    const ushort* __restrict__ Xh, const float* __restrict__ x2,
    unsigned* __restrict__ pck) {
  __shared__ __align__(16) char lds[32768];   // sA|sB staging ∪ Dk keys ∪ merge
  __shared__ float c2s[128];
  char* const sA = lds;
  char* const sB = lds + 16384;
  ushort* const Dk = (ushort*)lds;            // 128x128 u16 keys = 32 KB
  unsigned* const ck = (unsigned*)lds;        // merge [256][8] u32 = 8 KB

  const int tid = threadIdx.x;
  const int lane = tid & 63, wid = tid >> 6;
  const int fr = lane & 15, fq = lane >> 4;
  const int r0 = blockIdx.x * 128;
  const int grp = blockIdx.y;
  const int wr = (wid >> 1) * 64, wc = (wid & 1) * 64;
  const int srow = tid & 127, shalf = tid >> 7;

  unsigned keys[8];
  #pragma unroll
  for (int k = 0; k < 8; ++k) keys[k] = 0xFFFFFFFFu;

  for (int jt = 0; jt < (NN / NGRP) / 128; ++jt) {
    const int c0 = grp * (NN / NGRP) + jt * 128;
    __syncthreads();                         // prev tile scan done (c2s/Dk free)
    if (tid < 128) c2s[tid] = x2[c0 + tid];
    f32x4 acc[4][4] = {};
    for (int kt = 0; kt < HIDD; kt += 64) {
      __syncthreads();                       // prior LDS readers done
      // reg-staged: global bf16x8 -> swizzled ds_write (both-sides swizzle)
      #pragma unroll
      for (int q = 0; q < 4; ++q) {
        const int chunkid = q * 256 + tid;
        const int row = chunkid >> 3, cc = chunkid & 7;
        const bf16x8 va = *(const bf16x8*)(Xh + (size_t)(r0 + row) * HIDD + kt + cc * 8);
        const bf16x8 vb = *(const bf16x8*)(Xh + (size_t)(c0 + row) * HIDD + kt + cc * 8);
        const int wi = row * 128 + ((cc ^ (row & 7)) << 4);
        *(bf16x8*)(sA + wi) = va;
        *(bf16x8*)(sB + wi) = vb;
      }
      __syncthreads();                       // staged data visible
      #pragma unroll
      for (int kk = 0; kk < 2; ++kk) {
        bf16x8 bh[4];
        #pragma unroll
        for (int n = 0; n < 4; ++n) {
          const int br = wc + n * 16 + fr;
          bh[n] = *(const bf16x8*)(sB + br * 128 + (((kk * 4 + fq) ^ (br & 7)) << 4));
        }
        #pragma unroll
        for (int m = 0; m < 4; ++m) {
          const int ar = wr + m * 16 + fr;
          const bf16x8 a = *(const bf16x8*)(sA + ar * 128 + (((kk * 4 + fq) ^ (ar & 7)) << 4));
          #pragma unroll
          for (int n = 0; n < 4; ++n)
            acc[m][n] = __builtin_amdgcn_mfma_f32_16x16x32_bf16(a, bh[n], acc[m][n], 0, 0, 0);
        }
      }
    }
    __syncthreads();                         // all frag reads done; overlay Dk
    // write monotone-mapped f16 keys (score - 768 bias keeps f16 quantum small)
    #pragma unroll
    for (int n = 0; n < 4; ++n) {
      const int col = wc + n * 16 + fr;
      const float c2 = c2s[col] - 768.0f;
      #pragma unroll
      for (int m = 0; m < 4; ++m) {
        #pragma unroll
        for (int j = 0; j < 4; ++j) {
          const int row = wr + m * 16 + fq * 4 + j;
          const float s = c2 - 2.0f * acc[m][n][j];
          const ushort u = __half_as_ushort(__float2half(s));
          const ushort k16 = (u & 0x8000) ? (ushort)(~u) : (ushort)(u | 0x8000);
          Dk[row * 128 + ((col + row) & 127)] = k16;
        }
      }
    }
    __syncthreads();
    // scan: 256 threads, one half-row (64 cols) each, running top-8 keys
    {
      const int r = srow;
      for (int c = 0; c < 64; ++c) {
        const int col = shalf * 64 + c;
        const unsigned key =
            ((unsigned)Dk[r * 128 + ((col + r) & 127)] << 16) | (unsigned)(c0 + col);
        top8k_insert(key, keys);
      }
    }
  }
  // merge the two half-lists per row (overlay; barrier-guarded)
  __syncthreads();
  #pragma unroll
  for (int k = 0; k < 8; ++k) ck[tid * 8 + k] = keys[k];
  __syncthreads();
  if (tid < 128) {
    unsigned mk[8];
    #pragma unroll
    for (int k = 0; k < 8; ++k) mk[k] = ck[tid * 8 + k];
    const int src = tid + 128;
    #pragma unroll
    for (int k = 0; k < 8; ++k) top8k_insert(ck[src * 8 + k], mk);
    const size_t base = ((size_t)grp * NN + (r0 + tid)) * 8;   // [g][row][8]
    #pragma unroll
    for (int k = 0; k < 8; ++k) pck[base + k] = mk[k];
  }
}

// ---------- merge NGRP key lists -> per-row top-8 candidate indices ----------
__global__ __launch_bounds__(256) void cand_merge_kernel(const unsigned* __restrict__ pck,
    int* __restrict__ cand) {
  const int row = blockIdx.x * 256 + threadIdx.x;
  if (row >= NN) return;
  unsigned best[8];
  #pragma unroll
  for (int k = 0; k < 8; ++k) best[k] = 0xFFFFFFFFu;
  for (int g = 0; g < NGRP; ++g) {
    const size_t base = ((size_t)g * NN + row) * 8;
    #pragma unroll
    for (int k = 0; k < 8; ++k) top8k_insert(pck[base + k], best);
  }
  #pragma unroll
  for (int k = 0; k < 8; ++k) cand[row * 8 + k] = (int)(best[k] & 0xFFFFu);
}

// ---------- stage 2: exact fp32 refine of 8 candidates -> exact top-5 --------
__global__ __launch_bounds__(256) void refine_kernel(const float* __restrict__ X,
    const float* __restrict__ x2, const int* __restrict__ cand, int* __restrict__ knn) {
  const int row = blockIdx.x * 4 + (threadIdx.x >> 6);
  const int lane = threadIdx.x & 63;
  int c[8];
  #pragma unroll
  for (int k = 0; k < 8; ++k) c[k] = cand[row * 8 + k];
  const float4* xi = (const float4*)(X + (size_t)row * HIDD);
  float acc[8] = {};
  #pragma unroll
  for (int q = 0; q < 3; ++q) {
    const float4 a = xi[lane + q * 64];
    #pragma unroll
    for (int k = 0; k < 8; ++k) {
      const float4 b = ((const float4*)(X + (size_t)c[k] * HIDD))[lane + q * 64];
      acc[k] += a.x * b.x + a.y * b.y + a.z * b.z + a.w * b.w;
    }
  }
  #pragma unroll
  for (int k = 0; k < 8; ++k) {
    #pragma unroll
    for (int off = 32; off; off >>= 1) acc[k] += __shfl_down(acc[k], off);
  }
  if (lane == 0) {
    float d0 = 3e38f, d1 = 3e38f, d2 = 3e38f, d3 = 3e38f, d4 = 3e38f;
    int i0 = 0, i1 = 0, i2 = 0, i3 = 0, i4 = 0;
    #pragma unroll
    for (int k = 0; k < 8; ++k) {
      const float s = x2[c[k]] - 2.0f * acc[k];
      top5_insert(s, c[k], d0, d1, d2, d3, d4, i0, i1, i2, i3, i4);
    }
    knn[row * 5 + 0] = i0; knn[row * 5 + 1] = i1; knn[row * 5 + 2] = i2;
    knn[row * 5 + 3] = i3; knn[row * 5 + 4] = i4;
  }
}

// ---------- bf16 MFMA GEMM: C[8192,Nc] = A @ B^T + bias ----------------------
__global__ __launch_bounds__(256) void gemm_nt_mfma(const ushort* __restrict__ A,
    const ushort* __restrict__ B, const float* __restrict__ bias,
    float* __restrict__ C, int Nc, int K) {
  __shared__ char lds[32768];
  char* const pA = lds;
  char* const pB = lds + 16384;
  const int tid = threadIdx.x;
  const int lane = tid & 63, wid = tid >> 6;
  const int fr = lane & 15, fq = lane >> 4;
  const int r0 = blockIdx.x * 128;
  const int c0 = blockIdx.y * 128;
  const int wr = (wid >> 1) * 64, wc = (wid & 1) * 64;
  f32x4 acc[4][4] = {};
  for (int kt = 0; kt < K; kt += 64) {
    __syncthreads();
    #pragma unroll
    for (int q = 0; q < 4; ++q) {
      const int chunk = wid * 256 + q * 64 + lane;
      const int row = chunk >> 3;
      const int lc = (chunk & 7) ^ (row & 7);
      const int ld = wid * 4096 + q * 1024;
      stage16((const char*)A + ((size_t)(r0 + row) * K + kt) * 2 + (size_t)lc * 16, pA + ld);
      stage16((const char*)B + ((size_t)(c0 + row) * K + kt) * 2 + (size_t)lc * 16, pB + ld);
    }
    __syncthreads();
    #pragma unroll
    for (int kk = 0; kk < 2; ++kk) {
      bf16x8 ah[4], bh[4];
      #pragma unroll
      for (int m = 0; m < 4; ++m) {
        const int ar = wr + m * 16 + fr;
        ah[m] = *(const bf16x8*)(pA + ar * 128 + (((kk * 4 + fq) ^ (ar & 7)) << 4));
      }
      #pragma unroll
      for (int n = 0; n < 4; ++n) {
        const int br = wc + n * 16 + fr;
        bh[n] = *(const bf16x8*)(pB + br * 128 + (((kk * 4 + fq) ^ (br & 7)) << 4));
      }
      #pragma unroll
      for (int m = 0; m < 4; ++m)
        #pragma unroll
        for (int n = 0; n < 4; ++n)
          acc[m][n] = __builtin_amdgcn_mfma_f32_16x16x32_bf16(ah[m], bh[n], acc[m][n], 0, 0, 0);
    }
  }
  #pragma unroll
  for (int n = 0; n < 4; ++n) {
    const int cc = c0 + wc + n * 16 + fr;
    const float bs = bias[cc];
    #pragma unroll
    for (int m = 0; m < 4; ++m) {
      #pragma unroll
      for (int j = 0; j < 4; ++j) {
        const int rr = r0 + wr + m * 16 + fq * 4 + j;
        C[(size_t)rr * Nc + cc] = acc[m][n][j] + bs;
      }
    }
  }
}

// ---------- instance GATv2; xlr packed [N][1024]; ctx written bf16 -----------
__global__ __launch_bounds__(256) void inst_gat_kernel(const float* __restrict__ xlr,
    const int* __restrict__ knn, const float* __restrict__ att,
    const float* __restrict__ bias, const float* __restrict__ cmean,
    ushort* __restrict__ ctxh) {
  __shared__ float rows[7][512];   // 6 neighbor xl rows + own xr row
  __shared__ float sc[12];
  __shared__ float alpha[12];
  __shared__ int nbr[6];
  const int i = blockIdx.x;
  const int tid = threadIdx.x;
  if (tid < 5) nbr[tid] = knn[i * 5 + tid];
  else if (tid == 5) nbr[5] = i;   // explicit self loop
  __syncthreads();
  for (int t = tid; t < 7 * 128; t += 256) {
    const int rr = t >> 7, e4 = t & 127;
    const float* src = (rr < 6) ? (xlr + (size_t)nbr[rr] * 1024)
                                : (xlr + (size_t)i * 1024 + 512);
    ((float4*)rows[rr])[e4] = ((const float4*)src)[e4];
  }
  __syncthreads();
  const int lane = tid & 63, w = tid >> 6;
  for (int t = w; t < 12; t += 4) {
    const int e = t >> 1, h = t & 1;
    const float* ar = att + h * 256;
    float s = 0.f;
    #pragma unroll
    for (int q = 0; q < 4; ++q) {
      const int d = lane + q * 64;
      float v = rows[e][h * 256 + d] + rows[6][h * 256 + d];
      v = v > 0.f ? v : NEG * v;
      s += v * ar[d];
    }
    #pragma unroll
    for (int off = 32; off; off >>= 1) s += __shfl_down(s, off);
    if (lane == 0) sc[t] = s;
  }
  __syncthreads();
  if (tid < 2) {
    const int h = tid;
    float m = -3e38f;
    #pragma unroll
    for (int e = 0; e < 6; ++e) m = fmaxf(m, sc[e * 2 + h]);
    float ssum = 0.f;
    #pragma unroll
    for (int e = 0; e < 6; ++e) { float ex = expf(sc[e * 2 + h] - m); alpha[e * 2 + h] = ex; ssum += ex; }
    const float inv = 1.f / ssum;
    #pragma unroll
    for (int e = 0; e < 6; ++e) alpha[e * 2 + h] *= inv;
  }
  __syncthreads();
  for (int c = tid; c < OD; c += 256) {
    const int h = c >> 8;
    float acc = 0.f;
    #pragma unroll
    for (int e = 0; e < 6; ++e) acc += alpha[e * 2 + h] * rows[e][c];
    ctxh[(size_t)i * OD + c] = f2b(acc + bias[c] + cmean[c]);
  }
}

// ---------- fused epilogue: LN1 -> LN2 -> GELU -> 18-way classifier ----------
__global__ __launch_bounds__(256) void epilogue_kernel(const float* __restrict__ inst,
    const float* __restrict__ attn, const float* __restrict__ g1, const float* __restrict__ b1,
    const float* __restrict__ g2, const float* __restrict__ b2, const float* __restrict__ gw,
    const float* __restrict__ gb, const float* __restrict__ temp, float* __restrict__ out) {
  __shared__ float buf[HIDD];
  __shared__ float red[4];
  const int i = blockIdx.x;
  const int tid = threadIdx.x;
  const int lane = tid & 63, w = tid >> 6;
  size_t base = (size_t)i * HIDD;
  float v0 = inst[base + tid]       + attn[base + tid];
  float v1 = inst[base + tid + 256] + attn[base + tid + 256];
  float v2 = inst[base + tid + 512] + attn[base + tid + 512];

  float s = v0 + v1 + v2;
  #pragma unroll
  for (int off = 32; off; off >>= 1) s += __shfl_down(s, off);
  if (lane == 0) red[w] = s;
  __syncthreads();
  float mean = (red[0] + red[1] + red[2] + red[3]) * (1.f / HIDD);
  __syncthreads();
  float e0 = v0 - mean, e1 = v1 - mean, e2 = v2 - mean;
  s = e0 * e0 + e1 * e1 + e2 * e2;
  #pragma unroll
  for (int off = 32; off; off >>= 1) s += __shfl_down(s, off);
  if (lane == 0) red[w] = s;
  __syncthreads();
  float rstd = rsqrtf((red[0] + red[1] + red[2] + red[3]) * (1.f / HIDD) + LN_EPS);
  __syncthreads();
  float y0 = e0 * rstd * g1[tid]       + b1[tid];
  float y1 = e1 * rstd * g1[tid + 256] + b1[tid + 256];
  float y2 = e2 * rstd * g1[tid + 512] + b1[tid + 512];

  s = y0 + y1 + y2;
  #pragma unroll
  for (int off = 32; off; off >>= 1) s += __shfl_down(s, off);
  if (lane == 0) red[w] = s;
  __syncthreads();
  float mean2 = (red[0] + red[1] + red[2] + red[3]) * (1.f / HIDD);
  __syncthreads();
  float f0 = y0 - mean2, f1 = y1 - mean2, f2 = y2 - mean2;
  s = f0 * f0 + f1 * f1 + f2 * f2;
  #pragma unroll
  for (int off = 32; off; off >>= 1) s += __shfl_down(s, off);
  if (lane == 0) red[w] = s;
  __syncthreads();
  float rstd2 = rsqrtf((red[0] + red[1] + red[2] + red[3]) * (1.f / HIDD) + LN_EPS);
  float z0 = f0 * rstd2 * g2[tid]       + b2[tid];
  float z1 = f1 * rstd2 * g2[tid + 256] + b2[tid + 256];
  float z2 = f2 * rstd2 * g2[tid + 512] + b2[tid + 512];
  buf[tid]       = 0.5f * z0 * (1.f + erff(z0 * 0.70710678118654752f));
  buf[tid + 256] = 0.5f * z1 * (1.f + erff(z1 * 0.70710678118654752f));
  buf[tid + 512] = 0.5f * z2 * (1.f + erff(z2 * 0.70710678118654752f));
  __syncthreads();

  float invT = 1.f / temp[0];
  for (int c = w; c < NCLS; c += 4) {
    const float* wr = gw + (size_t)c * HIDD;
    float acc = 0.f;
    for (int d = lane; d < HIDD; d += 64) acc += buf[d] * wr[d];
    #pragma unroll
    for (int off = 32; off; off >>= 1) acc += __shfl_down(acc, off);
    if (lane == 0) out[(size_t)i * NCLS + c] = (acc + gb[c]) * invT;
  }
}

// ---------------------------------------------------------------------------
extern "C" void kernel_launch(void* const* d_in, const int* in_sizes, int n_in,
                              void* d_out, int out_size, void* d_ws, size_t ws_size,
                              hipStream_t stream) {
  (void)in_sizes; (void)n_in; (void)out_size; (void)ws_size;
  const float* X       = (const float*)d_in[0];
  const int*   cei     = (const int*)  d_in[1];
  const float* cemb    = (const float*)d_in[2];
  const float* gc_wl   = (const float*)d_in[3];
  const float* gc_bl   = (const float*)d_in[4];
  const float* gc_wr   = (const float*)d_in[5];
  const float* gc_br   = (const float*)d_in[6];
  const float* gc_att  = (const float*)d_in[7];
  const float* gc_bias = (const float*)d_in[8];
  const float* gi_wl   = (const float*)d_in[9];
  const float* gi_bl   = (const float*)d_in[10];
  const float* gi_wr   = (const float*)d_in[11];
  const float* gi_br   = (const float*)d_in[12];
  const float* gi_att  = (const float*)d_in[13];
  const float* gi_bias = (const float*)d_in[14];
  // d_in[15]=q_w, d_in[16]=q_b: cancel out of the forward value (seq_len 1)
  const float* ctx_w   = (const float*)d_in[17];
  const float* ctx_b   = (const float*)d_in[18];
  const float* wv      = (const float*)d_in[19];
  const float* bv      = (const float*)d_in[20];
  const float* wo      = (const float*)d_in[21];
  const float* bo      = (const float*)d_in[22];
  const float* ln1_g   = (const float*)d_in[23];
  const float* ln1_b   = (const float*)d_in[24];
  const float* ln2_g   = (const float*)d_in[25];
  const float* ln2_b   = (const float*)d_in[26];
  const float* gw_w    = (const float*)d_in[27];
  const float* gw_b    = (const float*)d_in[28];
  const float* temp    = (const float*)d_in[29];
  float* out = (float*)d_out;

  // ---- workspace layout (f32 units). R1,R2,R3 are 4.19M f32 each. ----
  // Order: prep1, prep2, dist, merge, refine, gemm_xlr, inst_gat, gemm_attn, epi
  // R1: pck (dist->merge) -> xlr head (gemm->inst_gat) -> attnb head
  // R2: T1 (prep1->prep2) -> xlr tail -> attnb mid
  // R3: Xh+wlrh (prep1 -> dist/gemm) -> ctxh (inst_gat->gemm_attn)
  // R4: x2, w3h, t1b, bp, bb, cand, knn, xlc, xrc, cmean (no overlays)
  float* ws  = (float*)d_ws;
  float* R1  = ws;
  float* R2  = R1 + (size_t)NN * OD;
  float* R3  = R2 + (size_t)NN * OD;
  float* R4  = R3 + (size_t)NN * OD;

  // R4 sublayout
  float* x2    = R4;                                   // 8192
  ushort* w3h  = (ushort*)(x2 + NN);                   // 768*512 bf16
  float* t1b   = (float*)(w3h + (size_t)HIDD * OD);    // 768
  float* bp    = t1b + HIDD;                           // 768
  float* bb    = bp + HIDD;                            // 1024 stacked bias
  int*   cand  = (int*)(bb + 2 * OD);                  // 8192*8
  int*   knn   = cand + NN * 8;                        // 8192*5
  float* xlc   = (float*)(knn + NN * 5);               // 18*512
  float* xrc   = xlc + NCLS * OD;                      // 18*512
  float* cmean = xrc + NCLS * OD;                      // 512

  // aliases
  unsigned* pck = (unsigned*)R1;                       // [16][8192][8] u32 = 4 MB
  float* xlr   = R1;                                   // 8192*1024 f32 (R1+R2)
  float* attnb = R1;                                   // 8192*768 f32 (R1+R2 head)
  float* T1    = R2;                                   // 768*512 f32 (dead before xlr)
  ushort* Xh   = (ushort*)R3;                          // 8192*768 bf16
  ushort* wlrh = (ushort*)(R3 + (size_t)NN * HIDD / 2);// 1024*768 bf16 stacked wl|wr
  ushort* ctxh = (ushort*)R3;                          // 8192*512 bf16 (Xh dead)

  // 1) all independent preamble tasks
  prep1_kernel<<<4431, 256, 0, stream>>>(X, Xh, x2, gi_wl, gi_wr, wlrh,
      cemb, gc_wl, gc_bl, gc_wr, gc_br, xlc, xrc,
      wv, ctx_w, T1, ctx_b, bv, t1b, gi_bl, gi_br, bb);
  // 2) W3 fold (bf16 out) + bp + class GAT
  prep2_kernel<<<1540, 256, 0, stream>>>(wo, T1, w3h, t1b, bo, bp,
      cei, xlc, xrc, gc_att, gc_bias, cmean);
  // 3) kNN approx pass (reg-staged MFMA + packed-key top-8)
  dist_topk_mfma<<<dim3(NN / 128, NGRP), 256, 0, stream>>>(Xh, x2, pck);
  // 4) merge candidate lists (pck dead after)
  cand_merge_kernel<<<NN / 256, 256, 0, stream>>>(pck, cand);
  // 5) exact fp32 refine -> knn
  refine_kernel<<<NN / 4, 256, 0, stream>>>(X, x2, cand, knn);
  // 6) fused xl|xr projection (overwrites pck region)
  gemm_nt_mfma<<<dim3(NN / 128, (2 * OD) / 128), 256, 0, stream>>>(Xh, wlrh, bb, xlr, 2 * OD, HIDD);
  // 7) GAT aggregate -> ctxh bf16 (overwrites Xh region; Xh dead)
  inst_gat_kernel<<<NN, 256, 0, stream>>>(xlr, knn, gi_att, gi_bias, cmean, ctxh);
  // 8) attn = ctxh @ w3h^T + bp (xlr dead; attnb overlays R1+R2)
  gemm_nt_mfma<<<dim3(NN / 128, HIDD / 128), 256, 0, stream>>>(ctxh, w3h, bp, attnb, HIDD, OD);
  // 9) LN -> LN -> GELU -> classifier
  epilogue_kernel<<<NN, 256, 0, stream>>>(X, attnb, ln1_g, ln1_b, ln2_g, ln2_b, gw_w, gw_b, temp, out);
}

// Round 10
// 809.732 us; speedup vs baseline: 1.3874x; 1.0183x over previous
//
#include <hip/hip_runtime.h>
#include <hip/hip_bf16.h>
#include <hip/hip_fp16.h>
#include <math.h>

#define NN 8192
#define HIDD 768
#define NCLS 18
#define OD 512          // HEADS*GD = 2*256
#define ETOT 342        // 324 class edges + 18 self loops
#define NEG 0.2f
#define LN_EPS 1e-5f

typedef __attribute__((ext_vector_type(8))) short bf16x8;
typedef __attribute__((ext_vector_type(4))) float f32x4;

// ---------- sorted top-5 insert (static indices, stays in registers) --------
__device__ __forceinline__ void top5_insert(float s, int idx,
    float& d0, float& d1, float& d2, float& d3, float& d4,
    int& i0, int& i1, int& i2, int& i3, int& i4) {
  if (s >= d4) return;
  if (s < d3) {
    d4 = d3; i4 = i3;
    if (s < d2) {
      d3 = d2; i3 = i2;
      if (s < d1) {
        d2 = d1; i2 = i1;
        if (s < d0) { d1 = d0; i1 = i0; d0 = s; i0 = idx; }
        else        { d1 = s;  i1 = idx; }
      } else { d2 = s; i2 = idx; }
    } else { d3 = s; i3 = idx; }
  } else { d4 = s; i4 = idx; }
}

// ---------- top-8 insert on packed u32 keys (rank-based, static indices) ----
__device__ __forceinline__ void top8k_insert(unsigned key, unsigned (&kk)[8]) {
  if (key >= kk[7]) return;
  int rank = 0;
  #pragma unroll
  for (int k = 0; k < 7; ++k) rank += (key >= kk[k]) ? 1 : 0;
  #pragma unroll
  for (int k = 7; k >= 1; --k) if (k > rank) kk[k] = kk[k-1];
  #pragma unroll
  for (int k = 0; k < 8; ++k) if (k == rank) kk[k] = key;
}

// ---------- async global->LDS 16B (used only in gemm_nt_mfma) ---------------
__device__ __forceinline__ void stage16(const void* g, void* l) {
  __builtin_amdgcn_global_load_lds(
      (const __attribute__((address_space(1))) unsigned int*)g,
      (__attribute__((address_space(3))) unsigned int*)l, 16, 0, 0);
}

__device__ __forceinline__ ushort f2b(float v) {
  __hip_bfloat16 b = __float2bfloat16(v);
  return *(ushort*)&b;
}

// ============ prep1 mega-kernel: all independent preamble tasks ==============
__global__ __launch_bounds__(256) void prep1_kernel(
    const float* __restrict__ X, ushort* __restrict__ Xh, float* __restrict__ x2,
    const float* __restrict__ gi_wl, const float* __restrict__ gi_wr,
    ushort* __restrict__ wlrh,
    const float* __restrict__ cemb, const float* __restrict__ gc_wl,
    const float* __restrict__ gc_bl, const float* __restrict__ gc_wr,
    const float* __restrict__ gc_br, float* __restrict__ xlc, float* __restrict__ xrc,
    const float* __restrict__ wv, const float* __restrict__ ctx_w, float* __restrict__ T1,
    const float* __restrict__ ctx_b, const float* __restrict__ bv, float* __restrict__ t1b,
    const float* __restrict__ gi_bl, const float* __restrict__ gi_br,
    float* __restrict__ bb) {
  const int bx = blockIdx.x, tid = threadIdx.x;
  if (bx < 2048) {                       // ---- rowcast + rownorm ----
    const int row = bx * 4 + (tid >> 6);
    const int lane = tid & 63;
    const float4* src = (const float4*)(X + (size_t)row * HIDD);
    ushort4* dst = (ushort4*)(Xh + (size_t)row * HIDD);
    float s = 0.f;
    #pragma unroll
    for (int q = 0; q < 3; ++q) {
      float4 v = src[lane + q * 64];
      s += v.x * v.x + v.y * v.y + v.z * v.z + v.w * v.w;
      dst[lane + q * 64] = make_ushort4(f2b(v.x), f2b(v.y), f2b(v.z), f2b(v.w));
    }
    #pragma unroll
    for (int off = 32; off; off >>= 1) s += __shfl_down(s, off);
    if (lane == 0) x2[row] = s;
  } else if (bx < 2816) {                // ---- weight casts ----
    int rel = bx - 2048;
    const float* src = gi_wl; ushort* dst = wlrh;
    if (rel >= 384) { rel -= 384; src = gi_wr; dst = wlrh + (size_t)OD * HIDD; }
    const int i = rel * 256 + tid;       // < 98304 = OD*HIDD/4
    float4 v = ((const float4*)src)[i];
    ((ushort4*)dst)[i] = make_ushort4(f2b(v.x), f2b(v.y), f2b(v.z), f2b(v.w));
  } else if (bx < 2888) {                // ---- class xlc/xrc ----
    int t = (bx - 2816) * 256 + tid;
    const float* W; const float* b; float* Y;
    if (t < NCLS * OD) { W = gc_wl; b = gc_bl; Y = xlc; }
    else { t -= NCLS * OD; W = gc_wr; b = gc_br; Y = xrc; }
    const int row = t / OD, o = t - row * OD;
    const float* xr = cemb + (size_t)row * HIDD;
    const float* wr = W + (size_t)o * HIDD;
    float acc = 0.f;
    for (int k = 0; k < HIDD; ++k) acc += xr[k] * wr[k];
    Y[t] = acc + b[o];
  } else if (bx < 4424) {                // ---- T1 = wv @ ctx_w ----
    const int idx = (bx - 2888) * 256 + tid;
    const int i = idx >> 9, j = idx & 511;
    float acc = 0.f;
    for (int k = 0; k < HIDD; ++k) acc += wv[(size_t)i * HIDD + k] * ctx_w[(size_t)k * OD + j];
    T1[idx] = acc;
  } else if (bx < 4427) {                // ---- t1b ----
    const int t = (bx - 4424) * 256 + tid;
    if (t < HIDD) {
      float acc = 0.f;
      for (int k = 0; k < HIDD; ++k) acc += ctx_b[k] * wv[(size_t)t * HIDD + k];
      t1b[t] = acc + bv[t];
    }
  } else {                               // ---- bias stack ----
    const int t = (bx - 4427) * 256 + tid;
    if (t < OD) bb[t] = gi_bl[t];
    else if (t < 2 * OD) bb[t] = gi_br[t - OD];
  }
}

// ============ prep2: W3 fold (bf16 out) + bp + class-graph GAT ===============
__global__ __launch_bounds__(256) void prep2_kernel(
    const float* __restrict__ wo, const float* __restrict__ T1,
    ushort* __restrict__ w3h, const float* __restrict__ t1b,
    const float* __restrict__ bo, float* __restrict__ bp,
    const int* __restrict__ cei, const float* __restrict__ xlc,
    const float* __restrict__ xrc, const float* __restrict__ gc_att,
    const float* __restrict__ gc_bias, float* __restrict__ cmean) {
  __shared__ float sc[ETOT * 2];
  __shared__ int es[ETOT], ed[ETOT];
  __shared__ float mx[NCLS][2], sm[NCLS][2];
  const int bx = blockIdx.x, tid = threadIdx.x;
  if (bx < 1536) {                       // ---- w3h ----
    const int idx = bx * 256 + tid;
    const int i = idx >> 9, j = idx & 511;
    float acc = 0.f;
    for (int k = 0; k < HIDD; ++k) acc += wo[(size_t)i * HIDD + k] * T1[(size_t)k * OD + j];
    w3h[idx] = f2b(acc);
  } else if (bx < 1539) {                // ---- bp ----
    const int t = (bx - 1536) * 256 + tid;
    if (t < HIDD) {
      float acc = 0.f;
      for (int k = 0; k < HIDD; ++k) acc += t1b[k] * wo[(size_t)t * HIDD + k];
      bp[t] = acc + bo[t];
    }
  } else {                               // ---- class GAT (1 block) ----
    for (int e = tid; e < ETOT; e += 256) {
      if (e < 324) { es[e] = cei[e]; ed[e] = cei[324 + e]; }
      else         { es[e] = e - 324; ed[e] = e - 324; }
    }
    __syncthreads();
    const int lane = tid & 63, w = tid >> 6;
    for (int t = w; t < ETOT * 2; t += 4) {
      const int e = t >> 1, h = t & 1;
      const float* xlr = xlc + (size_t)es[e] * OD + h * 256;
      const float* xrr = xrc + (size_t)ed[e] * OD + h * 256;
      const float* ar  = gc_att + h * 256;
      float s = 0.f;
      for (int d = lane; d < 256; d += 64) {
        float v = xlr[d] + xrr[d];
        v = v > 0.f ? v : NEG * v;
        s += v * ar[d];
      }
      #pragma unroll
      for (int off = 32; off; off >>= 1) s += __shfl_down(s, off);
      if (lane == 0) sc[t] = s;
    }
    __syncthreads();
    if (tid < NCLS * 2) {
      const int d = tid >> 1, h = tid & 1;
      float m = -3e38f;
      for (int e = 0; e < ETOT; ++e) if (ed[e] == d) m = fmaxf(m, sc[e * 2 + h]);
      float ssum = 0.f;
      for (int e = 0; e < ETOT; ++e) if (ed[e] == d) ssum += expf(sc[e * 2 + h] - m);
      mx[d][h] = m; sm[d][h] = 1.f / ssum;
    }
    __syncthreads();
    for (int t = tid; t < ETOT * 2; t += 256) {
      const int e = t >> 1, h = t & 1;
      sc[t] = expf(sc[t] - mx[ed[e]][h]) * sm[ed[e]][h];
    }
    __syncthreads();
    for (int c = tid; c < OD; c += 256) {
      const int h = c >> 8;
      float acc = 0.f;
      for (int e = 0; e < ETOT; ++e) acc += sc[e * 2 + h] * xlc[(size_t)es[e] * OD + c];
      cmean[c] = acc * (1.f / 18.f) + gc_bias[c];
    }
  }
}

// ---------- stage 1: SYMMETRIC bf16 MFMA distances, per-row approx top-8 -----
// One block per upper-triangle 128x128 tile (i<=j): compute -2*A_i·B_j^T once,
// scan it BOTH ways (rows-of-i over cols-of-j, and the transpose). Halves MFMA
// and panel fetch vs the full-matrix pass; scan work unchanged. Round-6 proven
// staging (reg-staged, swizzled, 33KB LDS union, <=128 VGPR, 4 blocks/CU).
// pck layout: [row][64 groups][8] u32 keys (monotone-f16(score-768)<<16 | col).
__global__ __launch_bounds__(256, 4) void dist_sym_mfma(
    const ushort* __restrict__ Xh, const float* __restrict__ x2,
    unsigned* __restrict__ pck) {
  if (blockIdx.y < blockIdx.x) return;        // upper triangle only
  __shared__ __align__(16) char lds[32768];   // sA|sB staging ∪ Dh scores ∪ ck
  __shared__ float x2i[128], x2j[128];
  char* const sA = lds;
  char* const sB = lds + 16384;
  __half* const Dh = (__half*)lds;            // [128][128] f16 (-2*dot), rotated
  unsigned* const ck = (unsigned*)lds;        // merge [256][8] u32

  const int tid = threadIdx.x;
  const int lane = tid & 63, wid = tid >> 6;
  const int fr = lane & 15, fq = lane >> 4;
  const int i0 = blockIdx.x * 128, j0 = blockIdx.y * 128;
  const int wr = (wid >> 1) * 64, wc = (wid & 1) * 64;
  const bool diag = (blockIdx.x == blockIdx.y);

  if (tid < 128) x2i[tid] = x2[i0 + tid];
  else x2j[tid - 128] = x2[j0 + tid - 128];

  f32x4 acc[4][4] = {};
  for (int kt = 0; kt < HIDD; kt += 64) {
    __syncthreads();                       // prior LDS readers done
    #pragma unroll
    for (int q = 0; q < 4; ++q) {
      const int chunkid = q * 256 + tid;
      const int row = chunkid >> 3, cc = chunkid & 7;
      const bf16x8 va = *(const bf16x8*)(Xh + (size_t)(i0 + row) * HIDD + kt + cc * 8);
      const bf16x8 vb = *(const bf16x8*)(Xh + (size_t)(j0 + row) * HIDD + kt + cc * 8);
      const int wi = row * 128 + ((cc ^ (row & 7)) << 4);
      *(bf16x8*)(sA + wi) = va;
      *(bf16x8*)(sB + wi) = vb;
    }
    __syncthreads();                       // staged data visible
    #pragma unroll
    for (int kk = 0; kk < 2; ++kk) {
      bf16x8 bh[4];
      #pragma unroll
      for (int n = 0; n < 4; ++n) {
        const int br = wc + n * 16 + fr;
        bh[n] = *(const bf16x8*)(sB + br * 128 + (((kk * 4 + fq) ^ (br & 7)) << 4));
      }
      #pragma unroll
      for (int m = 0; m < 4; ++m) {
        const int ar = wr + m * 16 + fr;
        const bf16x8 a = *(const bf16x8*)(sA + ar * 128 + (((kk * 4 + fq) ^ (ar & 7)) << 4));
        #pragma unroll
        for (int n = 0; n < 4; ++n)
          acc[m][n] = __builtin_amdgcn_mfma_f32_16x16x32_bf16(a, bh[n], acc[m][n], 0, 0, 0);
      }
    }
  }
  __syncthreads();                         // all frag reads done; overlay Dh
  // store f16(-2*dot), col slot rotated by row (row AND col reads conflict-light)
  #pragma unroll
  for (int n = 0; n < 4; ++n) {
    const int col = wc + n * 16 + fr;
    #pragma unroll
    for (int m = 0; m < 4; ++m) {
      #pragma unroll
      for (int j = 0; j < 4; ++j) {
        const int row = wr + m * 16 + fq * 4 + j;
        Dh[row * 128 + ((col + row) & 127)] = __float2half(-2.0f * acc[m][n][j]);
      }
    }
  }
  __syncthreads();

  unsigned ki[8], kj[8];
  #pragma unroll
  for (int k = 0; k < 8; ++k) { ki[k] = 0xFFFFFFFFu; kj[k] = 0xFFFFFFFFu; }
  const int r = tid & 127, h = tid >> 7;
  // phase-1 scan: rows-of-i over cols-of-j
  for (int c = 0; c < 64; ++c) {
    const int col = h * 64 + c;
    const float s = x2j[col] - 768.0f + __half2float(Dh[r * 128 + ((col + r) & 127)]);
    const ushort u = __half_as_ushort(__float2half(s));
    const ushort k16 = (u & 0x8000) ? (ushort)(~u) : (ushort)(u | 0x8000);
    top8k_insert(((unsigned)k16 << 16) | (unsigned)(j0 + col), ki);
  }
  // phase-2 scan: rows-of-j over cols-of-i (transpose read of Dh)
  if (!diag) {
    for (int c = 0; c < 64; ++c) {
      const int cr = h * 64 + c;
      const float s = x2i[cr] - 768.0f + __half2float(Dh[cr * 128 + ((r + cr) & 127)]);
      const ushort u = __half_as_ushort(__float2half(s));
      const ushort k16 = (u & 0x8000) ? (ushort)(~u) : (ushort)(u | 0x8000);
      top8k_insert(((unsigned)k16 << 16) | (unsigned)(i0 + cr), kj);
    }
  }
  __syncthreads();                         // Dh dead; ck may overlay
  // merge + write phase-1 lists: pck[(i0+r)][grp=blockIdx.y]
  #pragma unroll
  for (int k = 0; k < 8; ++k) ck[tid * 8 + k] = ki[k];
  __syncthreads();
  if (tid < 128) {
    unsigned mk[8];
    #pragma unroll
    for (int k = 0; k < 8; ++k) mk[k] = ck[tid * 8 + k];
    #pragma unroll
    for (int k = 0; k < 8; ++k) top8k_insert(ck[(tid + 128) * 8 + k], mk);
    const size_t base = ((size_t)(i0 + tid) * 64 + blockIdx.y) * 8;
    #pragma unroll
    for (int k = 0; k < 8; ++k) pck[base + k] = mk[k];
  }
  if (!diag) {                             // merge + write phase-2 lists
    __syncthreads();
    #pragma unroll
    for (int k = 0; k < 8; ++k) ck[tid * 8 + k] = kj[k];
    __syncthreads();
    if (tid < 128) {
      unsigned mk[8];
      #pragma unroll
      for (int k = 0; k < 8; ++k) mk[k] = ck[tid * 8 + k];
      #pragma unroll
      for (int k = 0; k < 8; ++k) top8k_insert(ck[(tid + 128) * 8 + k], mk);
      const size_t base = ((size_t)(j0 + tid) * 64 + blockIdx.x) * 8;
      #pragma unroll
      for (int k = 0; k < 8; ++k) pck[base + k] = mk[k];
    }
  }
}

// ---------- stage 2: butterfly-merge 64 key lists + exact fp32 refine --------
// One wave per row. Lane l loads group l's 8 keys (2KB/row coalesced), 6-step
// shfl_xor butterfly -> every lane holds the row's global top-8, then exact
// fp32 dot refine of the 8 candidates -> exact top-5.
__global__ __launch_bounds__(256) void merge_refine_kernel(
    const float* __restrict__ X, const float* __restrict__ x2,
    const unsigned* __restrict__ pck, int* __restrict__ knn) {
  const int row = blockIdx.x * 4 + (threadIdx.x >> 6);
  const int lane = threadIdx.x & 63;
  unsigned mk[8];
  #pragma unroll
  for (int k = 0; k < 8; ++k) mk[k] = pck[(size_t)row * 512 + lane * 8 + k];
  #pragma unroll
  for (int st = 1; st < 64; st <<= 1) {
    unsigned ok[8];
    #pragma unroll
    for (int k = 0; k < 8; ++k) ok[k] = __shfl_xor(mk[k], st);
    #pragma unroll
    for (int k = 0; k < 8; ++k) top8k_insert(ok[k], mk);
  }
  int c[8];
  #pragma unroll
  for (int k = 0; k < 8; ++k) c[k] = (int)(mk[k] & 0xFFFFu);
  // exact fp32 refine
  const float4* xi = (const float4*)(X + (size_t)row * HIDD);
  float acc[8] = {};
  #pragma unroll
  for (int q = 0; q < 3; ++q) {
    const float4 a = xi[lane + q * 64];
    #pragma unroll
    for (int k = 0; k < 8; ++k) {
      const float4 b = ((const float4*)(X + (size_t)c[k] * HIDD))[lane + q * 64];
      acc[k] += a.x * b.x + a.y * b.y + a.z * b.z + a.w * b.w;
    }
  }
  #pragma unroll
  for (int k = 0; k < 8; ++k) {
    #pragma unroll
    for (int off = 32; off; off >>= 1) acc[k] += __shfl_down(acc[k], off);
  }
  if (lane == 0) {
    float d0 = 3e38f, d1 = 3e38f, d2 = 3e38f, d3 = 3e38f, d4 = 3e38f;
    int i0 = 0, i1 = 0, i2 = 0, i3 = 0, i4 = 0;
    #pragma unroll
    for (int k = 0; k < 8; ++k) {
      const float s = x2[c[k]] - 2.0f * acc[k];
      top5_insert(s, c[k], d0, d1, d2, d3, d4, i0, i1, i2, i3, i4);
    }
    knn[row * 5 + 0] = i0; knn[row * 5 + 1] = i1; knn[row * 5 + 2] = i2;
    knn[row * 5 + 3] = i3; knn[row * 5 + 4] = i4;
  }
}

// ---------- bf16 MFMA GEMM: C[8192,Nc] = A @ B^T + bias ----------------------
__global__ __launch_bounds__(256) void gemm_nt_mfma(const ushort* __restrict__ A,
    const ushort* __restrict__ B, const float* __restrict__ bias,
    float* __restrict__ C, int Nc, int K) {
  __shared__ char lds[32768];
  char* const pA = lds;
  char* const pB = lds + 16384;
  const int tid = threadIdx.x;
  const int lane = tid & 63, wid = tid >> 6;
  const int fr = lane & 15, fq = lane >> 4;
  const int r0 = blockIdx.x * 128;
  const int c0 = blockIdx.y * 128;
  const int wr = (wid >> 1) * 64, wc = (wid & 1) * 64;
  f32x4 acc[4][4] = {};
  for (int kt = 0; kt < K; kt += 64) {
    __syncthreads();
    #pragma unroll
    for (int q = 0; q < 4; ++q) {
      const int chunk = wid * 256 + q * 64 + lane;
      const int row = chunk >> 3;
      const int lc = (chunk & 7) ^ (row & 7);
      const int ld = wid * 4096 + q * 1024;
      stage16((const char*)A + ((size_t)(r0 + row) * K + kt) * 2 + (size_t)lc * 16, pA + ld);
      stage16((const char*)B + ((size_t)(c0 + row) * K + kt) * 2 + (size_t)lc * 16, pB + ld);
    }
    __syncthreads();
    #pragma unroll
    for (int kk = 0; kk < 2; ++kk) {
      bf16x8 ah[4], bh[4];
      #pragma unroll
      for (int m = 0; m < 4; ++m) {
        const int ar = wr + m * 16 + fr;
        ah[m] = *(const bf16x8*)(pA + ar * 128 + (((kk * 4 + fq) ^ (ar & 7)) << 4));
      }
      #pragma unroll
      for (int n = 0; n < 4; ++n) {
        const int br = wc + n * 16 + fr;
        bh[n] = *(const bf16x8*)(pB + br * 128 + (((kk * 4 + fq) ^ (br & 7)) << 4));
      }
      #pragma unroll
      for (int m = 0; m < 4; ++m)
        #pragma unroll
        for (int n = 0; n < 4; ++n)
          acc[m][n] = __builtin_amdgcn_mfma_f32_16x16x32_bf16(ah[m], bh[n], acc[m][n], 0, 0, 0);
    }
  }
  #pragma unroll
  for (int n = 0; n < 4; ++n) {
    const int cc = c0 + wc + n * 16 + fr;
    const float bs = bias[cc];
    #pragma unroll
    for (int m = 0; m < 4; ++m) {
      #pragma unroll
      for (int j = 0; j < 4; ++j) {
        const int rr = r0 + wr + m * 16 + fq * 4 + j;
        C[(size_t)rr * Nc + cc] = acc[m][n][j] + bs;
      }
    }
  }
}

// ---------- instance GATv2; xlr packed [N][1024]; ctx written bf16 -----------
__global__ __launch_bounds__(256) void inst_gat_kernel(const float* __restrict__ xlr,
    const int* __restrict__ knn, const float* __restrict__ att,
    const float* __restrict__ bias, const float* __restrict__ cmean,
    ushort* __restrict__ ctxh) {
  __shared__ float rows[7][512];   // 6 neighbor xl rows + own xr row
  __shared__ float sc[12];
  __shared__ float alpha[12];
  __shared__ int nbr[6];
  const int i = blockIdx.x;
  const int tid = threadIdx.x;
  if (tid < 5) nbr[tid] = knn[i * 5 + tid];
  else if (tid == 5) nbr[5] = i;   // explicit self loop
  __syncthreads();
  for (int t = tid; t < 7 * 128; t += 256) {
    const int rr = t >> 7, e4 = t & 127;
    const float* src = (rr < 6) ? (xlr + (size_t)nbr[rr] * 1024)
                                : (xlr + (size_t)i * 1024 + 512);
    ((float4*)rows[rr])[e4] = ((const float4*)src)[e4];
  }
  __syncthreads();
  const int lane = tid & 63, w = tid >> 6;
  for (int t = w; t < 12; t += 4) {
    const int e = t >> 1, h = t & 1;
    const float* ar = att + h * 256;
    float s = 0.f;
    #pragma unroll
    for (int q = 0; q < 4; ++q) {
      const int d = lane + q * 64;
      float v = rows[e][h * 256 + d] + rows[6][h * 256 + d];
      v = v > 0.f ? v : NEG * v;
      s += v * ar[d];
    }
    #pragma unroll
    for (int off = 32; off; off >>= 1) s += __shfl_down(s, off);
    if (lane == 0) sc[t] = s;
  }
  __syncthreads();
  if (tid < 2) {
    const int h = tid;
    float m = -3e38f;
    #pragma unroll
    for (int e = 0; e < 6; ++e) m = fmaxf(m, sc[e * 2 + h]);
    float ssum = 0.f;
    #pragma unroll
    for (int e = 0; e < 6; ++e) { float ex = expf(sc[e * 2 + h] - m); alpha[e * 2 + h] = ex; ssum += ex; }
    const float inv = 1.f / ssum;
    #pragma unroll
    for (int e = 0; e < 6; ++e) alpha[e * 2 + h] *= inv;
  }
  __syncthreads();
  for (int c = tid; c < OD; c += 256) {
    const int h = c >> 8;
    float acc = 0.f;
    #pragma unroll
    for (int e = 0; e < 6; ++e) acc += alpha[e * 2 + h] * rows[e][c];
    ctxh[(size_t)i * OD + c] = f2b(acc + bias[c] + cmean[c]);
  }
}

// ---------- fused epilogue: LN1 -> LN2 -> GELU -> 18-way classifier ----------
__global__ __launch_bounds__(256) void epilogue_kernel(const float* __restrict__ inst,
    const float* __restrict__ attn, const float* __restrict__ g1, const float* __restrict__ b1,
    const float* __restrict__ g2, const float* __restrict__ b2, const float* __restrict__ gw,
    const float* __restrict__ gb, const float* __restrict__ temp, float* __restrict__ out) {
  __shared__ float buf[HIDD];
  __shared__ float red[4];
  const int i = blockIdx.x;
  const int tid = threadIdx.x;
  const int lane = tid & 63, w = tid >> 6;
  size_t base = (size_t)i * HIDD;
  float v0 = inst[base + tid]       + attn[base + tid];
  float v1 = inst[base + tid + 256] + attn[base + tid + 256];
  float v2 = inst[base + tid + 512] + attn[base + tid + 512];

  float s = v0 + v1 + v2;
  #pragma unroll
  for (int off = 32; off; off >>= 1) s += __shfl_down(s, off);
  if (lane == 0) red[w] = s;
  __syncthreads();
  float mean = (red[0] + red[1] + red[2] + red[3]) * (1.f / HIDD);
  __syncthreads();
  float e0 = v0 - mean, e1 = v1 - mean, e2 = v2 - mean;
  s = e0 * e0 + e1 * e1 + e2 * e2;
  #pragma unroll
  for (int off = 32; off; off >>= 1) s += __shfl_down(s, off);
  if (lane == 0) red[w] = s;
  __syncthreads();
  float rstd = rsqrtf((red[0] + red[1] + red[2] + red[3]) * (1.f / HIDD) + LN_EPS);
  __syncthreads();
  float y0 = e0 * rstd * g1[tid]       + b1[tid];
  float y1 = e1 * rstd * g1[tid + 256] + b1[tid + 256];
  float y2 = e2 * rstd * g1[tid + 512] + b1[tid + 512];

  s = y0 + y1 + y2;
  #pragma unroll
  for (int off = 32; off; off >>= 1) s += __shfl_down(s, off);
  if (lane == 0) red[w] = s;
  __syncthreads();
  float mean2 = (red[0] + red[1] + red[2] + red[3]) * (1.f / HIDD);
  __syncthreads();
  float f0 = y0 - mean2, f1 = y1 - mean2, f2 = y2 - mean2;
  s = f0 * f0 + f1 * f1 + f2 * f2;
  #pragma unroll
  for (int off = 32; off; off >>= 1) s += __shfl_down(s, off);
  if (lane == 0) red[w] = s;
  __syncthreads();
  float rstd2 = rsqrtf((red[0] + red[1] + red[2] + red[3]) * (1.f / HIDD) + LN_EPS);
  float z0 = f0 * rstd2 * g2[tid]       + b2[tid];
  float z1 = f1 * rstd2 * g2[tid + 256] + b2[tid + 256];
  float z2 = f2 * rstd2 * g2[tid + 512] + b2[tid + 512];
  buf[tid]       = 0.5f * z0 * (1.f + erff(z0 * 0.70710678118654752f));
  buf[tid + 256] = 0.5f * z1 * (1.f + erff(z1 * 0.70710678118654752f));
  buf[tid + 512] = 0.5f * z2 * (1.f + erff(z2 * 0.70710678118654752f));
  __syncthreads();

  float invT = 1.f / temp[0];
  for (int c = w; c < NCLS; c += 4) {
    const float* wr = gw + (size_t)c * HIDD;
    float acc = 0.f;
    for (int d = lane; d < HIDD; d += 64) acc += buf[d] * wr[d];
    #pragma unroll
    for (int off = 32; off; off >>= 1) acc += __shfl_down(acc, off);
    if (lane == 0) out[(size_t)i * NCLS + c] = (acc + gb[c]) * invT;
  }
}

// ---------------------------------------------------------------------------
extern "C" void kernel_launch(void* const* d_in, const int* in_sizes, int n_in,
                              void* d_out, int out_size, void* d_ws, size_t ws_size,
                              hipStream_t stream) {
  (void)in_sizes; (void)n_in; (void)out_size; (void)ws_size;
  const float* X       = (const float*)d_in[0];
  const int*   cei     = (const int*)  d_in[1];
  const float* cemb    = (const float*)d_in[2];
  const float* gc_wl   = (const float*)d_in[3];
  const float* gc_bl   = (const float*)d_in[4];
  const float* gc_wr   = (const float*)d_in[5];
  const float* gc_br   = (const float*)d_in[6];
  const float* gc_att  = (const float*)d_in[7];
  const float* gc_bias = (const float*)d_in[8];
  const float* gi_wl   = (const float*)d_in[9];
  const float* gi_bl   = (const float*)d_in[10];
  const float* gi_wr   = (const float*)d_in[11];
  const float* gi_br   = (const float*)d_in[12];
  const float* gi_att  = (const float*)d_in[13];
  const float* gi_bias = (const float*)d_in[14];
  // d_in[15]=q_w, d_in[16]=q_b: cancel out of the forward value (seq_len 1)
  const float* ctx_w   = (const float*)d_in[17];
  const float* ctx_b   = (const float*)d_in[18];
  const float* wv      = (const float*)d_in[19];
  const float* bv      = (const float*)d_in[20];
  const float* wo      = (const float*)d_in[21];
  const float* bo      = (const float*)d_in[22];
  const float* ln1_g   = (const float*)d_in[23];
  const float* ln1_b   = (const float*)d_in[24];
  const float* ln2_g   = (const float*)d_in[25];
  const float* ln2_b   = (const float*)d_in[26];
  const float* gw_w    = (const float*)d_in[27];
  const float* gw_b    = (const float*)d_in[28];
  const float* temp    = (const float*)d_in[29];
  float* out = (float*)d_out;

  // ---- workspace layout (f32 units). R1,R2,R3 are 4.19M f32 each. ----
  // Order: prep1, prep2, dist_sym, merge_refine, gemm_xlr, inst_gat, gemm_attn, epi
  // R1: pck [8192][64][8] u32 = 16 MiB exactly (dist->merge_refine)
  //     -> xlr head (gemm->inst_gat) -> attnb head
  // R2: T1 (prep1->prep2) -> xlr tail -> attnb mid
  // R3: Xh+wlrh (prep1 -> dist/gemm) -> ctxh (inst_gat->gemm_attn)
  // R4: x2, w3h, t1b, bp, bb, knn, xlc, xrc, cmean (no overlays)
  float* ws  = (float*)d_ws;
  float* R1  = ws;
  float* R2  = R1 + (size_t)NN * OD;
  float* R3  = R2 + (size_t)NN * OD;
  float* R4  = R3 + (size_t)NN * OD;

  // R4 sublayout
  float* x2    = R4;                                   // 8192
  ushort* w3h  = (ushort*)(x2 + NN);                   // 768*512 bf16
  float* t1b   = (float*)(w3h + (size_t)HIDD * OD);    // 768
  float* bp    = t1b + HIDD;                           // 768
  float* bb    = bp + HIDD;                            // 1024 stacked bias
  int*   knn   = (int*)(bb + 2 * OD);                  // 8192*5
  float* xlc   = (float*)(knn + NN * 5);               // 18*512
  float* xrc   = xlc + NCLS * OD;                      // 18*512
  float* cmean = xrc + NCLS * OD;                      // 512

  // aliases
  unsigned* pck = (unsigned*)R1;                       // [8192][64][8] u32 = 16 MiB
  float* xlr   = R1;                                   // 8192*1024 f32 (R1+R2)
  float* attnb = R1;                                   // 8192*768 f32 (R1+R2 head)
  float* T1    = R2;                                   // 768*512 f32 (dead before xlr)
  ushort* Xh   = (ushort*)R3;                          // 8192*768 bf16
  ushort* wlrh = (ushort*)(R3 + (size_t)NN * HIDD / 2);// 1024*768 bf16 stacked wl|wr
  ushort* ctxh = (ushort*)R3;                          // 8192*512 bf16 (Xh dead)

  // 1) all independent preamble tasks
  prep1_kernel<<<4431, 256, 0, stream>>>(X, Xh, x2, gi_wl, gi_wr, wlrh,
      cemb, gc_wl, gc_bl, gc_wr, gc_br, xlc, xrc,
      wv, ctx_w, T1, ctx_b, bv, t1b, gi_bl, gi_br, bb);
  // 2) W3 fold (bf16 out) + bp + class GAT
  prep2_kernel<<<1540, 256, 0, stream>>>(wo, T1, w3h, t1b, bo, bp,
      cei, xlc, xrc, gc_att, gc_bias, cmean);
  // 3) kNN approx pass: symmetric MFMA (upper triangle, both-way scan)
  dist_sym_mfma<<<dim3(64, 64), 256, 0, stream>>>(Xh, x2, pck);
  // 4) butterfly merge + exact fp32 refine -> knn (pck dead after)
  merge_refine_kernel<<<NN / 4, 256, 0, stream>>>(X, x2, pck, knn);
  // 5) fused xl|xr projection (overwrites pck region)
  gemm_nt_mfma<<<dim3(NN / 128, (2 * OD) / 128), 256, 0, stream>>>(Xh, wlrh, bb, xlr, 2 * OD, HIDD);
  // 6) GAT aggregate -> ctxh bf16 (overwrites Xh region; Xh dead)
  inst_gat_kernel<<<NN, 256, 0, stream>>>(xlr, knn, gi_att, gi_bias, cmean, ctxh);
  // 7) attn = ctxh @ w3h^T + bp (xlr dead; attnb overlays R1+R2)
  gemm_nt_mfma<<<dim3(NN / 128, HIDD / 128), 256, 0, stream>>>(ctxh, w3h, bp, attnb, HIDD, OD);
  // 8) LN -> LN -> GELU -> classifier
  epilogue_kernel<<<NN, 256, 0, stream>>>(X, attnb, ln1_g, ln1_b, ln2_g, ln2_b, gw_w, gw_b, temp, out);
}

// Round 11
// 762.777 us; speedup vs baseline: 1.4728x; 1.0616x over previous
//
#include <hip/hip_runtime.h>
#include <hip/hip_bf16.h>
#include <hip/hip_fp16.h>
#include <math.h>

#define NN 8192
#define HIDD 768
#define NCLS 18
#define OD 512          // HEADS*GD = 2*256
#define ETOT 342        // 324 class edges + 18 self loops
#define NEG 0.2f
#define LN_EPS 1e-5f

typedef __attribute__((ext_vector_type(8))) short bf16x8;
typedef __attribute__((ext_vector_type(4))) float f32x4;

// ---------- sorted top-5 insert (static indices, stays in registers) --------
__device__ __forceinline__ void top5_insert(float s, int idx,
    float& d0, float& d1, float& d2, float& d3, float& d4,
    int& i0, int& i1, int& i2, int& i3, int& i4) {
  if (s >= d4) return;
  if (s < d3) {
    d4 = d3; i4 = i3;
    if (s < d2) {
      d3 = d2; i3 = i2;
      if (s < d1) {
        d2 = d1; i2 = i1;
        if (s < d0) { d1 = d0; i1 = i0; d0 = s; i0 = idx; }
        else        { d1 = s;  i1 = idx; }
      } else { d2 = s; i2 = idx; }
    } else { d3 = s; i3 = idx; }
  } else { d4 = s; i4 = idx; }
}

// ---------- top-8 insert on packed u32 keys (rank-based, static indices) ----
__device__ __forceinline__ void top8k_insert(unsigned key, unsigned (&kk)[8]) {
  if (key >= kk[7]) return;
  int rank = 0;
  #pragma unroll
  for (int k = 0; k < 7; ++k) rank += (key >= kk[k]) ? 1 : 0;
  #pragma unroll
  for (int k = 7; k >= 1; --k) if (k > rank) kk[k] = kk[k-1];
  #pragma unroll
  for (int k = 0; k < 8; ++k) if (k == rank) kk[k] = key;
}

// ---------- async global->LDS 16B (used only in gemm_nt_mfma) ---------------
__device__ __forceinline__ void stage16(const void* g, void* l) {
  __builtin_amdgcn_global_load_lds(
      (const __attribute__((address_space(1))) unsigned int*)g,
      (__attribute__((address_space(3))) unsigned int*)l, 16, 0, 0);
}

__device__ __forceinline__ ushort f2b(float v) {
  __hip_bfloat16 b = __float2bfloat16(v);
  return *(ushort*)&b;
}

// ============ prep1 mega-kernel: independent preamble tasks ==================
// blocks [0,2048): rowcast X->Xh + x2
//        [2048,2816): cast gi_wl / gi_wr -> wlrh (bf16)
//        [2816,2888): xlc / xrc class projections (float4)
//        [2888,2891): t1b = wv @ ctx_b + bv (float4)
//        [2891,2895): bb = stack(gi_bl, gi_br)
__global__ __launch_bounds__(256) void prep1_kernel(
    const float* __restrict__ X, ushort* __restrict__ Xh, float* __restrict__ x2,
    const float* __restrict__ gi_wl, const float* __restrict__ gi_wr,
    ushort* __restrict__ wlrh,
    const float* __restrict__ cemb, const float* __restrict__ gc_wl,
    const float* __restrict__ gc_bl, const float* __restrict__ gc_wr,
    const float* __restrict__ gc_br, float* __restrict__ xlc, float* __restrict__ xrc,
    const float* __restrict__ wv, const float* __restrict__ ctx_b,
    const float* __restrict__ bv, float* __restrict__ t1b,
    const float* __restrict__ gi_bl, const float* __restrict__ gi_br,
    float* __restrict__ bb) {
  const int bx = blockIdx.x, tid = threadIdx.x;
  if (bx < 2048) {                       // ---- rowcast + rownorm ----
    const int row = bx * 4 + (tid >> 6);
    const int lane = tid & 63;
    const float4* src = (const float4*)(X + (size_t)row * HIDD);
    ushort4* dst = (ushort4*)(Xh + (size_t)row * HIDD);
    float s = 0.f;
    #pragma unroll
    for (int q = 0; q < 3; ++q) {
      float4 v = src[lane + q * 64];
      s += v.x * v.x + v.y * v.y + v.z * v.z + v.w * v.w;
      dst[lane + q * 64] = make_ushort4(f2b(v.x), f2b(v.y), f2b(v.z), f2b(v.w));
    }
    #pragma unroll
    for (int off = 32; off; off >>= 1) s += __shfl_down(s, off);
    if (lane == 0) x2[row] = s;
  } else if (bx < 2816) {                // ---- weight casts ----
    int rel = bx - 2048;
    const float* src = gi_wl; ushort* dst = wlrh;
    if (rel >= 384) { rel -= 384; src = gi_wr; dst = wlrh + (size_t)OD * HIDD; }
    const int i = rel * 256 + tid;       // < 98304 = OD*HIDD/4
    float4 v = ((const float4*)src)[i];
    ((ushort4*)dst)[i] = make_ushort4(f2b(v.x), f2b(v.y), f2b(v.z), f2b(v.w));
  } else if (bx < 2888) {                // ---- class xlc/xrc (float4) ----
    int t = (bx - 2816) * 256 + tid;
    const float* W; const float* b; float* Y;
    if (t < NCLS * OD) { W = gc_wl; b = gc_bl; Y = xlc; }
    else { t -= NCLS * OD; W = gc_wr; b = gc_br; Y = xrc; }
    const int row = t / OD, o = t - row * OD;
    const float4* xr4 = (const float4*)(cemb + (size_t)row * HIDD);
    const float4* wr4 = (const float4*)(W + (size_t)o * HIDD);
    float acc = 0.f;
    for (int k = 0; k < HIDD / 4; ++k) {
      const float4 a = xr4[k], w4 = wr4[k];
      acc += a.x * w4.x + a.y * w4.y + a.z * w4.z + a.w * w4.w;
    }
    Y[t] = acc + b[o];
  } else if (bx < 2891) {                // ---- t1b (float4) ----
    const int t = (bx - 2888) * 256 + tid;
    if (t < HIDD) {
      const float4* cb4 = (const float4*)ctx_b;
      const float4* wv4 = (const float4*)(wv + (size_t)t * HIDD);
      float acc = 0.f;
      for (int k = 0; k < HIDD / 4; ++k) {
        const float4 a = cb4[k], w4 = wv4[k];
        acc += a.x * w4.x + a.y * w4.y + a.z * w4.z + a.w * w4.w;
      }
      t1b[t] = acc + bv[t];
    }
  } else {                               // ---- bias stack ----
    const int t = (bx - 2891) * 256 + tid;
    if (t < OD) bb[t] = gi_bl[t];
    else if (t < 2 * OD) bb[t] = gi_br[t - OD];
  }
}

// ============ tiled fp32 NN GEMM: C[M,N] = A[M,K] @ B[K,N] ===================
// 64x64 tile, 256 threads, 4x4 per thread; writes f32 (Cf) or bf16 (Ch).
__global__ __launch_bounds__(256) void gemm_nn_f32(const float* __restrict__ A,
    const float* __restrict__ B, float* __restrict__ Cf, ushort* __restrict__ Ch,
    int M, int N, int K) {
  __shared__ float As[64][33];
  __shared__ float Bs[32][65];
  const int tid = threadIdx.x, tx = tid & 15, ty = tid >> 4;
  const int r0 = blockIdx.x * 64, c0 = blockIdx.y * 64;
  float acc[4][4] = {};
  for (int kt = 0; kt < K; kt += 32) {
    __syncthreads();
    #pragma unroll
    for (int l = 0; l < 8; ++l) {
      const int idx = l * 256 + tid;
      const int m = idx >> 5, k = idx & 31;
      As[m][k] = A[(size_t)(r0 + m) * K + kt + k];
      const int k2 = idx >> 6, n = idx & 63;
      Bs[k2][n] = B[(size_t)(kt + k2) * N + c0 + n];
    }
    __syncthreads();
    #pragma unroll
    for (int k = 0; k < 32; ++k) {
      float a[4], b[4];
      #pragma unroll
      for (int i = 0; i < 4; ++i) a[i] = As[ty * 4 + i][k];
      #pragma unroll
      for (int j = 0; j < 4; ++j) b[j] = Bs[k][tx * 4 + j];
      #pragma unroll
      for (int i = 0; i < 4; ++i)
        #pragma unroll
        for (int j = 0; j < 4; ++j) acc[i][j] += a[i] * b[j];
    }
  }
  #pragma unroll
  for (int i = 0; i < 4; ++i) {
    const int r = r0 + ty * 4 + i;
    #pragma unroll
    for (int j = 0; j < 4; ++j) {
      const int c = c0 + tx * 4 + j;
      if (Ch) Ch[(size_t)r * N + c] = f2b(acc[i][j]);
      else    Cf[(size_t)r * N + c] = acc[i][j];
    }
  }
}

// ============ prep2: bp (float4) + class-graph GAT ===========================
__global__ __launch_bounds__(256) void prep2_kernel(
    const float* __restrict__ wo, const float* __restrict__ t1b,
    const float* __restrict__ bo, float* __restrict__ bp,
    const int* __restrict__ cei, const float* __restrict__ xlc,
    const float* __restrict__ xrc, const float* __restrict__ gc_att,
    const float* __restrict__ gc_bias, float* __restrict__ cmean) {
  __shared__ float sc[ETOT * 2];
  __shared__ int es[ETOT], ed[ETOT];
  __shared__ float mx[NCLS][2], sm[NCLS][2];
  const int bx = blockIdx.x, tid = threadIdx.x;
  if (bx < 3) {                          // ---- bp ----
    const int t = bx * 256 + tid;
    if (t < HIDD) {
      const float4* tb4 = (const float4*)t1b;
      const float4* wo4 = (const float4*)(wo + (size_t)t * HIDD);
      float acc = 0.f;
      for (int k = 0; k < HIDD / 4; ++k) {
        const float4 a = tb4[k], w4 = wo4[k];
        acc += a.x * w4.x + a.y * w4.y + a.z * w4.z + a.w * w4.w;
      }
      bp[t] = acc + bo[t];
    }
  } else {                               // ---- class GAT (1 block) ----
    for (int e = tid; e < ETOT; e += 256) {
      if (e < 324) { es[e] = cei[e]; ed[e] = cei[324 + e]; }
      else         { es[e] = e - 324; ed[e] = e - 324; }
    }
    __syncthreads();
    const int lane = tid & 63, w = tid >> 6;
    for (int t = w; t < ETOT * 2; t += 4) {
      const int e = t >> 1, h = t & 1;
      const float* xlr = xlc + (size_t)es[e] * OD + h * 256;
      const float* xrr = xrc + (size_t)ed[e] * OD + h * 256;
      const float* ar  = gc_att + h * 256;
      float s = 0.f;
      for (int d = lane; d < 256; d += 64) {
        float v = xlr[d] + xrr[d];
        v = v > 0.f ? v : NEG * v;
        s += v * ar[d];
      }
      #pragma unroll
      for (int off = 32; off; off >>= 1) s += __shfl_down(s, off);
      if (lane == 0) sc[t] = s;
    }
    __syncthreads();
    if (tid < NCLS * 2) {
      const int d = tid >> 1, h = tid & 1;
      float m = -3e38f;
      for (int e = 0; e < ETOT; ++e) if (ed[e] == d) m = fmaxf(m, sc[e * 2 + h]);
      float ssum = 0.f;
      for (int e = 0; e < ETOT; ++e) if (ed[e] == d) ssum += expf(sc[e * 2 + h] - m);
      mx[d][h] = m; sm[d][h] = 1.f / ssum;
    }
    __syncthreads();
    for (int t = tid; t < ETOT * 2; t += 256) {
      const int e = t >> 1, h = t & 1;
      sc[t] = expf(sc[t] - mx[ed[e]][h]) * sm[ed[e]][h];
    }
    __syncthreads();
    for (int c = tid; c < OD; c += 256) {
      const int h = c >> 8;
      float acc = 0.f;
      for (int e = 0; e < ETOT; ++e) acc += sc[e * 2 + h] * xlc[(size_t)es[e] * OD + c];
      cmean[c] = acc * (1.f / 18.f) + gc_bias[c];
    }
  }
}

// ---------- stage 1: SYMMETRIC bf16 MFMA distances, per-row approx top-8 -----
// Compact triangular grid: 2080 blocks, block t -> (bx<=by) panel pair.
// Compute -2*A_i·B_j^T once, scan BOTH directions. Round-6 proven staging
// (reg-staged, swizzled, 33KB LDS union, <=128 VGPR, 4 blocks/CU).
// pck layout: [row][64 groups][8] u32 keys (monotone-f16(score-768)<<16 | col).
__global__ __launch_bounds__(256, 4) void dist_sym_mfma(
    const ushort* __restrict__ Xh, const float* __restrict__ x2,
    unsigned* __restrict__ pck) {
  __shared__ __align__(16) char lds[32768];   // sA|sB staging ∪ Dh scores ∪ ck
  __shared__ float x2i[128], x2j[128];
  char* const sA = lds;
  char* const sB = lds + 16384;
  __half* const Dh = (__half*)lds;            // [128][128] f16 (-2*dot), rotated
  unsigned* const ck = (unsigned*)lds;        // merge [256][8] u32

  // triangular decode: t -> (bx, by) with bx <= by
  const int t = blockIdx.x;
  int by = (int)((sqrtf(8.0f * (float)t + 1.0f) - 1.0f) * 0.5f);
  while ((by + 1) * (by + 2) / 2 <= t) ++by;
  while (by * (by + 1) / 2 > t) --by;
  const int bx = t - by * (by + 1) / 2;

  const int tid = threadIdx.x;
  const int lane = tid & 63, wid = tid >> 6;
  const int fr = lane & 15, fq = lane >> 4;
  const int i0 = bx * 128, j0 = by * 128;
  const int wr = (wid >> 1) * 64, wc = (wid & 1) * 64;
  const bool diag = (bx == by);

  if (tid < 128) x2i[tid] = x2[i0 + tid];
  else x2j[tid - 128] = x2[j0 + tid - 128];

  f32x4 acc[4][4] = {};
  for (int kt = 0; kt < HIDD; kt += 64) {
    __syncthreads();                       // prior LDS readers done
    #pragma unroll
    for (int q = 0; q < 4; ++q) {
      const int chunkid = q * 256 + tid;
      const int row = chunkid >> 3, cc = chunkid & 7;
      const bf16x8 va = *(const bf16x8*)(Xh + (size_t)(i0 + row) * HIDD + kt + cc * 8);
      const bf16x8 vb = *(const bf16x8*)(Xh + (size_t)(j0 + row) * HIDD + kt + cc * 8);
      const int wi = row * 128 + ((cc ^ (row & 7)) << 4);
      *(bf16x8*)(sA + wi) = va;
      *(bf16x8*)(sB + wi) = vb;
    }
    __syncthreads();                       // staged data visible
    #pragma unroll
    for (int kk = 0; kk < 2; ++kk) {
      bf16x8 bh[4];
      #pragma unroll
      for (int n = 0; n < 4; ++n) {
        const int br = wc + n * 16 + fr;
        bh[n] = *(const bf16x8*)(sB + br * 128 + (((kk * 4 + fq) ^ (br & 7)) << 4));
      }
      #pragma unroll
      for (int m = 0; m < 4; ++m) {
        const int ar = wr + m * 16 + fr;
        const bf16x8 a = *(const bf16x8*)(sA + ar * 128 + (((kk * 4 + fq) ^ (ar & 7)) << 4));
        #pragma unroll
        for (int n = 0; n < 4; ++n)
          acc[m][n] = __builtin_amdgcn_mfma_f32_16x16x32_bf16(a, bh[n], acc[m][n], 0, 0, 0);
      }
    }
  }
  __syncthreads();                         // all frag reads done; overlay Dh
  // store f16(-2*dot), col slot rotated by row (row AND col reads conflict-light)
  #pragma unroll
  for (int n = 0; n < 4; ++n) {
    const int col = wc + n * 16 + fr;
    #pragma unroll
    for (int m = 0; m < 4; ++m) {
      #pragma unroll
      for (int j = 0; j < 4; ++j) {
        const int row = wr + m * 16 + fq * 4 + j;
        Dh[row * 128 + ((col + row) & 127)] = __float2half(-2.0f * acc[m][n][j]);
      }
    }
  }
  __syncthreads();

  unsigned ki[8], kj[8];
  #pragma unroll
  for (int k = 0; k < 8; ++k) { ki[k] = 0xFFFFFFFFu; kj[k] = 0xFFFFFFFFu; }
  const int r = tid & 127, h = tid >> 7;
  // phase-1 scan: rows-of-i over cols-of-j
  for (int c = 0; c < 64; ++c) {
    const int col = h * 64 + c;
    const float s = x2j[col] - 768.0f + __half2float(Dh[r * 128 + ((col + r) & 127)]);
    const ushort u = __half_as_ushort(__float2half(s));
    const ushort k16 = (u & 0x8000) ? (ushort)(~u) : (ushort)(u | 0x8000);
    top8k_insert(((unsigned)k16 << 16) | (unsigned)(j0 + col), ki);
  }
  // phase-2 scan: rows-of-j over cols-of-i (transpose read of Dh)
  if (!diag) {
    for (int c = 0; c < 64; ++c) {
      const int cr = h * 64 + c;
      const float s = x2i[cr] - 768.0f + __half2float(Dh[cr * 128 + ((r + cr) & 127)]);
      const ushort u = __half_as_ushort(__float2half(s));
      const ushort k16 = (u & 0x8000) ? (ushort)(~u) : (ushort)(u | 0x8000);
      top8k_insert(((unsigned)k16 << 16) | (unsigned)(i0 + cr), kj);
    }
  }
  __syncthreads();                         // Dh dead; ck may overlay
  // merge + write phase-1 lists: pck[(i0+r)][grp=by]
  #pragma unroll
  for (int k = 0; k < 8; ++k) ck[tid * 8 + k] = ki[k];
  __syncthreads();
  if (tid < 128) {
    unsigned mk[8];
    #pragma unroll
    for (int k = 0; k < 8; ++k) mk[k] = ck[tid * 8 + k];
    #pragma unroll
    for (int k = 0; k < 8; ++k) top8k_insert(ck[(tid + 128) * 8 + k], mk);
    const size_t base = ((size_t)(i0 + tid) * 64 + by) * 8;
    #pragma unroll
    for (int k = 0; k < 8; ++k) pck[base + k] = mk[k];
  }
  if (!diag) {                             // merge + write phase-2 lists
    __syncthreads();
    #pragma unroll
    for (int k = 0; k < 8; ++k) ck[tid * 8 + k] = kj[k];
    __syncthreads();
    if (tid < 128) {
      unsigned mk[8];
      #pragma unroll
      for (int k = 0; k < 8; ++k) mk[k] = ck[tid * 8 + k];
      #pragma unroll
      for (int k = 0; k < 8; ++k) top8k_insert(ck[(tid + 128) * 8 + k], mk);
      const size_t base = ((size_t)(j0 + tid) * 64 + bx) * 8;
      #pragma unroll
      for (int k = 0; k < 8; ++k) pck[base + k] = mk[k];
    }
  }
}

// ---------- stage 2: butterfly-merge 64 key lists + exact fp32 refine --------
__global__ __launch_bounds__(256) void merge_refine_kernel(
    const float* __restrict__ X, const float* __restrict__ x2,
    const unsigned* __restrict__ pck, int* __restrict__ knn) {
  const int row = blockIdx.x * 4 + (threadIdx.x >> 6);
  const int lane = threadIdx.x & 63;
  unsigned mk[8];
  #pragma unroll
  for (int k = 0; k < 8; ++k) mk[k] = pck[(size_t)row * 512 + lane * 8 + k];
  #pragma unroll
  for (int st = 1; st < 64; st <<= 1) {
    unsigned ok[8];
    #pragma unroll
    for (int k = 0; k < 8; ++k) ok[k] = __shfl_xor(mk[k], st);
    #pragma unroll
    for (int k = 0; k < 8; ++k) top8k_insert(ok[k], mk);
  }
  int c[8];
  #pragma unroll
  for (int k = 0; k < 8; ++k) c[k] = (int)(mk[k] & 0xFFFFu);
  // exact fp32 refine
  const float4* xi = (const float4*)(X + (size_t)row * HIDD);
  float acc[8] = {};
  #pragma unroll
  for (int q = 0; q < 3; ++q) {
    const float4 a = xi[lane + q * 64];
    #pragma unroll
    for (int k = 0; k < 8; ++k) {
      const float4 b = ((const float4*)(X + (size_t)c[k] * HIDD))[lane + q * 64];
      acc[k] += a.x * b.x + a.y * b.y + a.z * b.z + a.w * b.w;
    }
  }
  #pragma unroll
  for (int k = 0; k < 8; ++k) {
    #pragma unroll
    for (int off = 32; off; off >>= 1) acc[k] += __shfl_down(acc[k], off);
  }
  if (lane == 0) {
    float d0 = 3e38f, d1 = 3e38f, d2 = 3e38f, d3 = 3e38f, d4 = 3e38f;
    int i0 = 0, i1 = 0, i2 = 0, i3 = 0, i4 = 0;
    #pragma unroll
    for (int k = 0; k < 8; ++k) {
      const float s = x2[c[k]] - 2.0f * acc[k];
      top5_insert(s, c[k], d0, d1, d2, d3, d4, i0, i1, i2, i3, i4);
    }
    knn[row * 5 + 0] = i0; knn[row * 5 + 1] = i1; knn[row * 5 + 2] = i2;
    knn[row * 5 + 3] = i3; knn[row * 5 + 4] = i4;
  }
}

// ---------- bf16 MFMA GEMM: C[8192,Nc] = A @ B^T + bias ----------------------
__global__ __launch_bounds__(256) void gemm_nt_mfma(const ushort* __restrict__ A,
    const ushort* __restrict__ B, const float* __restrict__ bias,
    float* __restrict__ C, int Nc, int K) {
  __shared__ char lds[32768];
  char* const pA = lds;
  char* const pB = lds + 16384;
  const int tid = threadIdx.x;
  const int lane = tid & 63, wid = tid >> 6;
  const int fr = lane & 15, fq = lane >> 4;
  const int r0 = blockIdx.x * 128;
  const int c0 = blockIdx.y * 128;
  const int wr = (wid >> 1) * 64, wc = (wid & 1) * 64;
  f32x4 acc[4][4] = {};
  for (int kt = 0; kt < K; kt += 64) {
    __syncthreads();
    #pragma unroll
    for (int q = 0; q < 4; ++q) {
      const int chunk = wid * 256 + q * 64 + lane;
      const int row = chunk >> 3;
      const int lc = (chunk & 7) ^ (row & 7);
      const int ld = wid * 4096 + q * 1024;
      stage16((const char*)A + ((size_t)(r0 + row) * K + kt) * 2 + (size_t)lc * 16, pA + ld);
      stage16((const char*)B + ((size_t)(c0 + row) * K + kt) * 2 + (size_t)lc * 16, pB + ld);
    }
    __syncthreads();
    #pragma unroll
    for (int kk = 0; kk < 2; ++kk) {
      bf16x8 ah[4], bh[4];
      #pragma unroll
      for (int m = 0; m < 4; ++m) {
        const int ar = wr + m * 16 + fr;
        ah[m] = *(const bf16x8*)(pA + ar * 128 + (((kk * 4 + fq) ^ (ar & 7)) << 4));
      }
      #pragma unroll
      for (int n = 0; n < 4; ++n) {
        const int br = wc + n * 16 + fr;
        bh[n] = *(const bf16x8*)(pB + br * 128 + (((kk * 4 + fq) ^ (br & 7)) << 4));
      }
      #pragma unroll
      for (int m = 0; m < 4; ++m)
        #pragma unroll
        for (int n = 0; n < 4; ++n)
          acc[m][n] = __builtin_amdgcn_mfma_f32_16x16x32_bf16(ah[m], bh[n], acc[m][n], 0, 0, 0);
    }
  }
  #pragma unroll
  for (int n = 0; n < 4; ++n) {
    const int cc = c0 + wc + n * 16 + fr;
    const float bs = bias[cc];
    #pragma unroll
    for (int m = 0; m < 4; ++m) {
      #pragma unroll
      for (int j = 0; j < 4; ++j) {
        const int rr = r0 + wr + m * 16 + fq * 4 + j;
        C[(size_t)rr * Nc + cc] = acc[m][n][j] + bs;
      }
    }
  }
}

// ---------- instance GATv2; xlr packed [N][1024]; ctx written bf16 -----------
__global__ __launch_bounds__(256) void inst_gat_kernel(const float* __restrict__ xlr,
    const int* __restrict__ knn, const float* __restrict__ att,
    const float* __restrict__ bias, const float* __restrict__ cmean,
    ushort* __restrict__ ctxh) {
  __shared__ float rows[7][512];   // 6 neighbor xl rows + own xr row
  __shared__ float sc[12];
  __shared__ float alpha[12];
  __shared__ int nbr[6];
  const int i = blockIdx.x;
  const int tid = threadIdx.x;
  if (tid < 5) nbr[tid] = knn[i * 5 + tid];
  else if (tid == 5) nbr[5] = i;   // explicit self loop
  __syncthreads();
  for (int t = tid; t < 7 * 128; t += 256) {
    const int rr = t >> 7, e4 = t & 127;
    const float* src = (rr < 6) ? (xlr + (size_t)nbr[rr] * 1024)
                                : (xlr + (size_t)i * 1024 + 512);
    ((float4*)rows[rr])[e4] = ((const float4*)src)[e4];
  }
  __syncthreads();
  const int lane = tid & 63, w = tid >> 6;
  for (int t = w; t < 12; t += 4) {
    const int e = t >> 1, h = t & 1;
    const float* ar = att + h * 256;
    float s = 0.f;
    #pragma unroll
    for (int q = 0; q < 4; ++q) {
      const int d = lane + q * 64;
      float v = rows[e][h * 256 + d] + rows[6][h * 256 + d];
      v = v > 0.f ? v : NEG * v;
      s += v * ar[d];
    }
    #pragma unroll
    for (int off = 32; off; off >>= 1) s += __shfl_down(s, off);
    if (lane == 0) sc[t] = s;
  }
  __syncthreads();
  if (tid < 2) {
    const int h = tid;
    float m = -3e38f;
    #pragma unroll
    for (int e = 0; e < 6; ++e) m = fmaxf(m, sc[e * 2 + h]);
    float ssum = 0.f;
    #pragma unroll
    for (int e = 0; e < 6; ++e) { float ex = expf(sc[e * 2 + h] - m); alpha[e * 2 + h] = ex; ssum += ex; }
    const float inv = 1.f / ssum;
    #pragma unroll
    for (int e = 0; e < 6; ++e) alpha[e * 2 + h] *= inv;
  }
  __syncthreads();
  for (int c = tid; c < OD; c += 256) {
    const int h = c >> 8;
    float acc = 0.f;
    #pragma unroll
    for (int e = 0; e < 6; ++e) acc += alpha[e * 2 + h] * rows[e][c];
    ctxh[(size_t)i * OD + c] = f2b(acc + bias[c] + cmean[c]);
  }
}

// ---------- fused epilogue: LN1 -> LN2 -> GELU -> 18-way classifier ----------
__global__ __launch_bounds__(256) void epilogue_kernel(const float* __restrict__ inst,
    const float* __restrict__ attn, const float* __restrict__ g1, const float* __restrict__ b1,
    const float* __restrict__ g2, const float* __restrict__ b2, const float* __restrict__ gw,
    const float* __restrict__ gb, const float* __restrict__ temp, float* __restrict__ out) {
  __shared__ float buf[HIDD];
  __shared__ float red[4];
  const int i = blockIdx.x;
  const int tid = threadIdx.x;
  const int lane = tid & 63, w = tid >> 6;
  size_t base = (size_t)i * HIDD;
  float v0 = inst[base + tid]       + attn[base + tid];
  float v1 = inst[base + tid + 256] + attn[base + tid + 256];
  float v2 = inst[base + tid + 512] + attn[base + tid + 512];

  float s = v0 + v1 + v2;
  #pragma unroll
  for (int off = 32; off; off >>= 1) s += __shfl_down(s, off);
  if (lane == 0) red[w] = s;
  __syncthreads();
  float mean = (red[0] + red[1] + red[2] + red[3]) * (1.f / HIDD);
  __syncthreads();
  float e0 = v0 - mean, e1 = v1 - mean, e2 = v2 - mean;
  s = e0 * e0 + e1 * e1 + e2 * e2;
  #pragma unroll
  for (int off = 32; off; off >>= 1) s += __shfl_down(s, off);
  if (lane == 0) red[w] = s;
  __syncthreads();
  float rstd = rsqrtf((red[0] + red[1] + red[2] + red[3]) * (1.f / HIDD) + LN_EPS);
  __syncthreads();
  float y0 = e0 * rstd * g1[tid]       + b1[tid];
  float y1 = e1 * rstd * g1[tid + 256] + b1[tid + 256];
  float y2 = e2 * rstd * g1[tid + 512] + b1[tid + 512];

  s = y0 + y1 + y2;
  #pragma unroll
  for (int off = 32; off; off >>= 1) s += __shfl_down(s, off);
  if (lane == 0) red[w] = s;
  __syncthreads();
  float mean2 = (red[0] + red[1] + red[2] + red[3]) * (1.f / HIDD);
  __syncthreads();
  float f0 = y0 - mean2, f1 = y1 - mean2, f2 = y2 - mean2;
  s = f0 * f0 + f1 * f1 + f2 * f2;
  #pragma unroll
  for (int off = 32; off; off >>= 1) s += __shfl_down(s, off);
  if (lane == 0) red[w] = s;
  __syncthreads();
  float rstd2 = rsqrtf((red[0] + red[1] + red[2] + red[3]) * (1.f / HIDD) + LN_EPS);
  float z0 = f0 * rstd2 * g2[tid]       + b2[tid];
  float z1 = f1 * rstd2 * g2[tid + 256] + b2[tid + 256];
  float z2 = f2 * rstd2 * g2[tid + 512] + b2[tid + 512];
  buf[tid]       = 0.5f * z0 * (1.f + erff(z0 * 0.70710678118654752f));
  buf[tid + 256] = 0.5f * z1 * (1.f + erff(z1 * 0.70710678118654752f));
  buf[tid + 512] = 0.5f * z2 * (1.f + erff(z2 * 0.70710678118654752f));
  __syncthreads();

  float invT = 1.f / temp[0];
  for (int c = w; c < NCLS; c += 4) {
    const float* wr = gw + (size_t)c * HIDD;
    float acc = 0.f;
    for (int d = lane; d < HIDD; d += 64) acc += buf[d] * wr[d];
    #pragma unroll
    for (int off = 32; off; off >>= 1) acc += __shfl_down(acc, off);
    if (lane == 0) out[(size_t)i * NCLS + c] = (acc + gb[c]) * invT;
  }
}

// ---------------------------------------------------------------------------
extern "C" void kernel_launch(void* const* d_in, const int* in_sizes, int n_in,
                              void* d_out, int out_size, void* d_ws, size_t ws_size,
                              hipStream_t stream) {
  (void)in_sizes; (void)n_in; (void)out_size; (void)ws_size;
  const float* X       = (const float*)d_in[0];
  const int*   cei     = (const int*)  d_in[1];
  const float* cemb    = (const float*)d_in[2];
  const float* gc_wl   = (const float*)d_in[3];
  const float* gc_bl   = (const float*)d_in[4];
  const float* gc_wr   = (const float*)d_in[5];
  const float* gc_br   = (const float*)d_in[6];
  const float* gc_att  = (const float*)d_in[7];
  const float* gc_bias = (const float*)d_in[8];
  const float* gi_wl   = (const float*)d_in[9];
  const float* gi_bl   = (const float*)d_in[10];
  const float* gi_wr   = (const float*)d_in[11];
  const float* gi_br   = (const float*)d_in[12];
  const float* gi_att  = (const float*)d_in[13];
  const float* gi_bias = (const float*)d_in[14];
  // d_in[15]=q_w, d_in[16]=q_b: cancel out of the forward value (seq_len 1)
  const float* ctx_w   = (const float*)d_in[17];
  const float* ctx_b   = (const float*)d_in[18];
  const float* wv      = (const float*)d_in[19];
  const float* bv      = (const float*)d_in[20];
  const float* wo      = (const float*)d_in[21];
  const float* bo      = (const float*)d_in[22];
  const float* ln1_g   = (const float*)d_in[23];
  const float* ln1_b   = (const float*)d_in[24];
  const float* ln2_g   = (const float*)d_in[25];
  const float* ln2_b   = (const float*)d_in[26];
  const float* gw_w    = (const float*)d_in[27];
  const float* gw_b    = (const float*)d_in[28];
  const float* temp    = (const float*)d_in[29];
  float* out = (float*)d_out;

  // ---- workspace layout (f32 units). R1,R2,R3 are 4.19M f32 each. ----
  // Order: prep1, gemmT1, gemmW3, prep2, dist_sym, merge_refine,
  //        gemm_xlr, inst_gat, gemm_attn, epi
  // R1: pck [8192][64][8] u32 = 16 MiB (dist->merge_refine)
  //     -> xlr head (gemm->inst_gat) -> attnb head
  // R2: T1 (gemmT1->gemmW3) -> xlr tail -> attnb mid
  // R3: Xh+wlrh (prep1 -> dist/gemm) -> ctxh (inst_gat->gemm_attn)
  // R4: x2, w3h, t1b, bp, bb, knn, xlc, xrc, cmean (no overlays)
  float* ws  = (float*)d_ws;
  float* R1  = ws;
  float* R2  = R1 + (size_t)NN * OD;
  float* R3  = R2 + (size_t)NN * OD;
  float* R4  = R3 + (size_t)NN * OD;

  // R4 sublayout
  float* x2    = R4;                                   // 8192
  ushort* w3h  = (ushort*)(x2 + NN);                   // 768*512 bf16
  float* t1b   = (float*)(w3h + (size_t)HIDD * OD);    // 768
  float* bp    = t1b + HIDD;                           // 768
  float* bb    = bp + HIDD;                            // 1024 stacked bias
  int*   knn   = (int*)(bb + 2 * OD);                  // 8192*5
  float* xlc   = (float*)(knn + NN * 5);               // 18*512
  float* xrc   = xlc + NCLS * OD;                      // 18*512
  float* cmean = xrc + NCLS * OD;                      // 512

  // aliases
  unsigned* pck = (unsigned*)R1;                       // [8192][64][8] u32 = 16 MiB
  float* xlr   = R1;                                   // 8192*1024 f32 (R1+R2)
  float* attnb = R1;                                   // 8192*768 f32 (R1+R2 head)
  float* T1    = R2;                                   // 768*512 f32 (dead before xlr)
  ushort* Xh   = (ushort*)R3;                          // 8192*768 bf16
  ushort* wlrh = (ushort*)(R3 + (size_t)NN * HIDD / 2);// 1024*768 bf16 stacked wl|wr
  ushort* ctxh = (ushort*)R3;                          // 8192*512 bf16 (Xh dead)

  // 1) independent preamble tasks
  prep1_kernel<<<2895, 256, 0, stream>>>(X, Xh, x2, gi_wl, gi_wr, wlrh,
      cemb, gc_wl, gc_bl, gc_wr, gc_br, xlc, xrc,
      wv, ctx_b, bv, t1b, gi_bl, gi_br, bb);
  // 2) T1 = wv @ ctx_w (tiled fp32)
  gemm_nn_f32<<<dim3(HIDD / 64, OD / 64), 256, 0, stream>>>(wv, ctx_w, T1, nullptr, HIDD, OD, HIDD);
  // 3) w3h = bf16(wo @ T1) (tiled fp32, bf16 out)
  gemm_nn_f32<<<dim3(HIDD / 64, OD / 64), 256, 0, stream>>>(wo, T1, nullptr, w3h, HIDD, OD, HIDD);
  // 4) bp + class GAT
  prep2_kernel<<<4, 256, 0, stream>>>(wo, t1b, bo, bp, cei, xlc, xrc, gc_att, gc_bias, cmean);
  // 5) kNN approx pass: symmetric MFMA, compact triangular grid
  dist_sym_mfma<<<2080, 256, 0, stream>>>(Xh, x2, pck);
  // 6) butterfly merge + exact fp32 refine -> knn (pck dead after)
  merge_refine_kernel<<<NN / 4, 256, 0, stream>>>(X, x2, pck, knn);
  // 7) fused xl|xr projection (overwrites pck region)
  gemm_nt_mfma<<<dim3(NN / 128, (2 * OD) / 128), 256, 0, stream>>>(Xh, wlrh, bb, xlr, 2 * OD, HIDD);
  // 8) GAT aggregate -> ctxh bf16 (overwrites Xh region; Xh dead)
  inst_gat_kernel<<<NN, 256, 0, stream>>>(xlr, knn, gi_att, gi_bias, cmean, ctxh);
  // 9) attn = ctxh @ w3h^T + bp (xlr dead; attnb overlays R1+R2)
  gemm_nt_mfma<<<dim3(NN / 128, HIDD / 128), 256, 0, stream>>>(ctxh, w3h, bp, attnb, HIDD, OD);
  // 10) LN -> LN -> GELU -> classifier
  epilogue_kernel<<<NN, 256, 0, stream>>>(X, attnb, ln1_g, ln1_b, ln2_g, ln2_b, gw_w, gw_b, temp, out);
}